// Round 6
// baseline (1437.465 us; speedup 1.0000x reference)
//
#include <hip/hip_runtime.h>
#include <math.h>

#define Nn 50000
#define Ee 400000
#define FSz 256
#define HD_ 512
#define Bb 1024
#define ECAP 65536

// World model (settled R5): ALL float inputs fp32; OUTPUT fp32 (reference
// returns float32 logits; the "bf16" in the harness label is hardcoded text).
static __device__ __forceinline__ int clampi(int v, int lo, int hi){
    return v < lo ? lo : (v > hi ? hi : v);
}

// K0: init workspace (ws is poisoned 0xAA before every launch)
__global__ __launch_bounds__(256) void k_init(int* uid, int* deg, int* fill, int* cnt){
    int i = blockIdx.x * 256 + threadIdx.x;
    if(i < Nn) uid[i] = -1;
    if(i < 1024){ deg[i] = 0; fill[i] = 0; }
    if(i == 0) cnt[0] = 0;
}

// K1: fold attn_l/attn_r into gat_fc_w -> wl,wr [256][8] fp32
// el[n,h] = (x@W)[n,h,:]·attn_l[h,:] = x[n,:] @ (W @ attn_l[h,:])  (exact)
__global__ __launch_bounds__(256) void k_fold(const float* __restrict__ W,
                                              const float* __restrict__ al,
                                              const float* __restrict__ ar,
                                              float* __restrict__ wl, float* __restrict__ wr){
    int f = threadIdx.x;
    for(int h = 0; h < 8; h++){
        float sl = 0.f, sr = 0.f;
        for(int d = 0; d < 64; d++){
            float w = W[f*512 + h*64 + d];
            sl += w * al[h*64 + d];
            sr += w * ar[h*64 + d];
        }
        wl[f*8 + h] = sl; wr[f*8 + h] = sr;
    }
}

// K2: el,er for all N nodes (features @ wl / wr) — scalar, boring
__global__ __launch_bounds__(256) void k_eler(const float* __restrict__ features,
                                              const float* __restrict__ wl, const float* __restrict__ wr,
                                              float* __restrict__ el, float* __restrict__ er){
    int n = blockIdx.x * 256 + threadIdx.x;
    if(n >= Nn) return;
    const float* row = features + (size_t)n * FSz;
    float al[8] = {0,0,0,0,0,0,0,0};
    float ar[8] = {0,0,0,0,0,0,0,0};
    for(int f = 0; f < 256; f++){
        float x = row[f];
        #pragma unroll
        for(int h = 0; h < 8; h++){
            al[h] += x * wl[f*8 + h];
            ar[h] += x * wr[f*8 + h];
        }
    }
    #pragma unroll
    for(int h = 0; h < 8; h++){ el[n*8 + h] = al[h]; er[n*8 + h] = ar[h]; }
}

// K3: assign dense ids to unique selected nodes
__global__ __launch_bounds__(256) void k_mark(const int* __restrict__ url, int* uid, int* unode, int* cnt){
    int b = blockIdx.x * 256 + threadIdx.x;
    if(b >= Bb) return;
    int n = clampi(url[b] - 1, 0, Nn - 1);    // url is 1-based
    int old = atomicCAS(&uid[n], -1, -2);
    if(old == -1){
        int id = atomicAdd(cnt, 1);
        unode[id] = n;
        uid[n] = id;
    }
}

// K4: per-unique-node in-degree
__global__ __launch_bounds__(256) void k_count(const int* __restrict__ dst, const int* __restrict__ uid,
                                               int* __restrict__ deg){
    int e = blockIdx.x * 256 + threadIdx.x;
    if(e >= Ee) return;
    int d = dst[e];
    if((unsigned)d >= (unsigned)Nn) return;
    int u = uid[d];
    if(u >= 0) atomicAdd(&deg[u], 1);
}

// K5: exclusive prefix scan over 1024 degrees -> off[0..1024]
__global__ __launch_bounds__(1024) void k_scan(const int* __restrict__ deg, int* __restrict__ off){
    __shared__ int s[1024];
    int t = threadIdx.x;
    s[t] = deg[t];
    __syncthreads();
    for(int d2 = 1; d2 < 1024; d2 <<= 1){
        int v = (t >= d2) ? s[t - d2] : 0;
        __syncthreads();
        s[t] += v;
        __syncthreads();
    }
    if(t == 0) off[0] = 0;
    off[t + 1] = s[t];
}

// K6: CSR scatter
__global__ __launch_bounds__(256) void k_scatter(const int* __restrict__ dst,
                                                 const int* __restrict__ uid, const int* __restrict__ off,
                                                 int* __restrict__ fill, int* __restrict__ elist){
    int e = blockIdx.x * 256 + threadIdx.x;
    if(e >= Ee) return;
    int d = dst[e];
    if((unsigned)d >= (unsigned)Nn) return;
    int u = uid[d];
    if(u < 0) return;
    int pos = off[u] + atomicAdd(&fill[u], 1);
    if(pos < ECAP) elist[pos] = e;
}

// K6b: per (selected node, head): serial softmax over its edges -> normalized aval
__global__ __launch_bounds__(256) void k_soft(const int* __restrict__ src,
                                              const int* __restrict__ elist, const int* __restrict__ off,
                                              const float* __restrict__ el, const float* __restrict__ er,
                                              const int* __restrict__ unode, const int* __restrict__ cnt,
                                              float* __restrict__ aval){
    int idx = blockIdx.x * 256 + threadIdx.x;
    int u = idx >> 3, h = idx & 7;
    if(u >= cnt[0]) return;
    int n = unode[u];
    float ern = er[n*8 + h];
    int e0 = off[u], e1 = off[u + 1];
    if(e1 > ECAP) e1 = ECAP;
    if(e1 <= e0) return;
    float m = -1e30f;
    for(int ei = e0; ei < e1; ei++){
        int s = clampi(src[elist[ei]], 0, Nn - 1);
        float v = el[s*8 + h] + ern;
        v = v > 0.f ? v : 0.2f * v;
        m = fmaxf(m, v);
    }
    float sum = 0.f;
    for(int ei = e0; ei < e1; ei++){
        int s = clampi(src[elist[ei]], 0, Nn - 1);
        float v = el[s*8 + h] + ern;
        v = v > 0.f ? v : 0.2f * v;
        float w = expf(v - m);          // v <= m -> w in (0,1]
        sum += w;
        aval[(size_t)ei*8 + h] = w;
    }
    float inv = 1.0f / fmaxf(sum, 1e-20f);
    for(int ei = e0; ei < e1; ei++)
        aval[(size_t)ei*8 + h] *= inv;
}

// K7: per unique node: alpha-combine source feature rows, then one 256x512 GEMV
// (gat_fc_w) + residual GEMV (gat_res_w). All scalar, naive indexing.
__global__ __launch_bounds__(256) void k_gat(const float* __restrict__ features,
                                             const float* __restrict__ Wfc,
                                             const float* __restrict__ Wres,
                                             const float* __restrict__ bias,
                                             const int* __restrict__ src,
                                             const int* __restrict__ cnt, const int* __restrict__ unode,
                                             const int* __restrict__ off, const int* __restrict__ elist,
                                             const float* __restrict__ aval,
                                             float* __restrict__ gemb){
    int u = blockIdx.x;
    if(u >= cnt[0]) return;
    int t = threadIdx.x;
    int n = unode[u];

    __shared__ float cxs[8][256];   // alpha-combined source rows, per head
    __shared__ float fres[256];     // features[n] for residual

    fres[t] = features[(size_t)n * FSz + t];

    float cx[8] = {0,0,0,0,0,0,0,0};
    int e0 = off[u], e1 = off[u + 1];
    if(e1 > ECAP) e1 = ECAP;
    for(int ei = e0; ei < e1; ei++){
        int s = clampi(src[elist[ei]], 0, Nn - 1);
        float x = features[(size_t)s * FSz + t];
        const float* av = &aval[(size_t)ei * 8];
        #pragma unroll
        for(int h = 0; h < 8; h++) cx[h] += av[h] * x;
    }
    #pragma unroll
    for(int h = 0; h < 8; h++) cxs[h][t] = cx[h];
    __syncthreads();

    // outputs o = pass*256 + t; rst[n,h,d] = sum_f cxs[h][f]*Wfc[f,o] ; o = h*64+d
    #pragma unroll
    for(int pass = 0; pass < 2; pass++){
        int o = pass*256 + t;
        int h = o >> 6;
        float acc = bias[o];
        for(int f = 0; f < 256; f++){
            acc += cxs[h][f] * Wfc[f*512 + o];
            acc += fres[f]   * Wres[f*512 + o];
        }
        gemb[(size_t)u * HD_ + o] = acc;
    }
}

// K8: per batch element: LN1 -> qkv -> attn(seq=8, heads=8) -> fc -> LN2 -> pool -> logits
__global__ __launch_bounds__(256) void k_mha(const int* __restrict__ url, const int* __restrict__ uid,
                                             const float* __restrict__ gemb,
                                             const float* __restrict__ lng, const float* __restrict__ lnb,
                                             const float* __restrict__ wq, const float* __restrict__ wk,
                                             const float* __restrict__ wvp, const float* __restrict__ fcw,
                                             const float* __restrict__ fcb, const float* __restrict__ mlg,
                                             const float* __restrict__ mlb, const float* __restrict__ outw,
                                             const float* __restrict__ outb, float* __restrict__ out){
    __shared__ float xr[512];
    __shared__ float xn[512];          // LN1 output == residual
    __shared__ float qkv[3][4096];     // q,k,v as [seq=8][512], col = nh*64 + d
    __shared__ float ov[4096];         // attn@v, [seq=8][512]
    __shared__ float sc[512];          // scores [nh][qq][kk]
    __shared__ float yy[512];
    __shared__ float mu8[8], rs8[8];
    __shared__ float pooled[64];

    int b = blockIdx.x, t = threadIdx.x;
    int n = clampi(url[b] - 1, 0, Nn - 1);
    int u = uid[n];
    if(u < 0) u = 0;                   // cannot happen; defensive
    const float* gp = gemb + (size_t)u * HD_;
    xr[t] = gp[t]; xr[t + 256] = gp[t + 256];
    __syncthreads();
    if(t < 8){
        float s = 0.f, s2 = 0.f;
        for(int d = 0; d < 64; d++){ float v = xr[t*64 + d]; s += v; s2 += v * v; }
        float mu = s * (1.0f/64.0f);
        float var = s2 * (1.0f/64.0f) - mu * mu;
        mu8[t] = mu; rs8[t] = rsqrtf(fmaxf(var, 0.0f) + 1e-6f);
    }
    __syncthreads();
    #pragma unroll
    for(int p = 0; p < 2; p++){
        int i = p*256 + t; int q = i >> 6, d = i & 63;
        xn[i] = (xr[i] - mu8[q]) * rs8[q] * lng[d] + lnb[d];
    }
    __syncthreads();
    // ---- qkv projections, naive: q[qq, c] = sum_d xn[qq*64+d] * wq[d*512+c] ----
    {
        const float* wm[3] = { wq, wk, wvp };
        for(int m3 = 0; m3 < 3; m3++){
            const float* w = wm[m3];
            for(int qq = 0; qq < 8; qq++){
                #pragma unroll
                for(int p = 0; p < 2; p++){
                    int c = p*256 + t;
                    float a = 0.f;
                    for(int d = 0; d < 64; d++) a += xn[qq*64 + d] * w[d*512 + c];
                    qkv[m3][qq*512 + c] = a;
                }
            }
        }
    }
    __syncthreads();
    // ---- scores sc[nh*64 + qq*8 + kk] = (q[qq,nh,:]·k[kk,nh,:]) / 8 ----
    #pragma unroll
    for(int p = 0; p < 2; p++){
        int idx = p*256 + t;
        int nh = idx >> 6, qq = (idx >> 3) & 7, kk = idx & 7;
        float s = 0.f;
        for(int d = 0; d < 64; d++)
            s += qkv[0][qq*512 + nh*64 + d] * qkv[1][kk*512 + nh*64 + d];
        sc[idx] = s * 0.125f;
    }
    __syncthreads();
    if(t < 64){                        // t = nh*8 + qq ; softmax over kk
        float mx = -1e30f;
        #pragma unroll
        for(int k = 0; k < 8; k++) mx = fmaxf(mx, sc[t*8 + k]);
        float e[8]; float s = 0.f;
        #pragma unroll
        for(int k = 0; k < 8; k++){ e[k] = expf(sc[t*8 + k] - mx); s += e[k]; }
        float inv = 1.0f / s;
        #pragma unroll
        for(int k = 0; k < 8; k++) sc[t*8 + k] = e[k] * inv;
    }
    __syncthreads();
    // ---- attn @ v : ov[qq*512 + nh*64+d] = sum_kk sc[nh*64+qq*8+kk] * v[kk*512+nh*64+d] ----
    #pragma unroll
    for(int p = 0; p < 16; p++){
        int idx = p*256 + t;
        int qq = idx >> 9, o = idx & 511, nh = o >> 6;
        float s = 0.f;
        #pragma unroll
        for(int kk = 0; kk < 8; kk++) s += sc[nh*64 + qq*8 + kk] * qkv[2][kk*512 + o];
        ov[idx] = s;
    }
    __syncthreads();
    // ---- fc + bias + residual : yy[qq*64+dd] = sum_k ov[qq*512+k]*fcw[k*64+dd] + fcb[dd] + xn ----
    #pragma unroll
    for(int p = 0; p < 2; p++){
        int o = p*256 + t;
        int qq = o >> 6, dd = o & 63;
        float a = fcb[dd];
        for(int k2 = 0; k2 < 512; k2++) a += ov[qq*512 + k2] * fcw[k2*64 + dd];
        yy[o] = a + xn[o];
    }
    __syncthreads();
    if(t < 8){
        float s = 0.f, s2 = 0.f;
        for(int d = 0; d < 64; d++){ float v = yy[t*64 + d]; s += v; s2 += v * v; }
        float mu = s * (1.0f/64.0f);
        float var = s2 * (1.0f/64.0f) - mu * mu;
        mu8[t] = mu; rs8[t] = rsqrtf(fmaxf(var, 0.0f) + 1e-6f);
    }
    __syncthreads();
    if(t < 64){
        float g = mlg[t], bb = mlb[t];
        float s = 0.f;
        #pragma unroll
        for(int qq = 0; qq < 8; qq++)
            s += (yy[qq*64 + t] - mu8[qq]) * rs8[qq] * g + bb;
        pooled[t] = s;
    }
    __syncthreads();
    if(t < 2){
        float s = outb[t];
        for(int d = 0; d < 64; d++) s += pooled[d] * outw[d*2 + t];
        out[b*2 + t] = s;              // fp32 output (reference returns float32)
    }
}

extern "C" void kernel_launch(void* const* d_in, const int* in_sizes, int n_in,
                              void* d_out, int out_size, void* d_ws, size_t ws_size,
                              hipStream_t stream){
    (void)in_sizes; (void)n_in; (void)out_size; (void)ws_size;
    const float* features  = (const float*)d_in[0];
    const int*   src       = (const int*)d_in[1];
    const int*   dst       = (const int*)d_in[2];
    const int*   url       = (const int*)d_in[3];
    const float* gat_fc_w  = (const float*)d_in[4];
    const float* attn_l    = (const float*)d_in[5];
    const float* attn_r    = (const float*)d_in[6];
    const float* gat_res_w = (const float*)d_in[7];
    const float* gat_bias  = (const float*)d_in[8];
    const float* ln_g      = (const float*)d_in[9];
    const float* ln_b      = (const float*)d_in[10];
    const float* wq        = (const float*)d_in[11];
    const float* wk        = (const float*)d_in[12];
    const float* wv        = (const float*)d_in[13];
    const float* fc_w      = (const float*)d_in[14];
    const float* fc_b      = (const float*)d_in[15];
    const float* mha_ln_g  = (const float*)d_in[16];
    const float* mha_ln_b  = (const float*)d_in[17];
    const float* out_w     = (const float*)d_in[18];
    const float* out_b     = (const float*)d_in[19];

    char* base = (char*)d_ws;
    size_t cur = 0;
    auto alloc = [&](size_t nbytes) -> void* {
        void* p = base + cur;
        cur = (cur + nbytes + 255) & ~(size_t)255;
        return p;
    };
    float* wl    = (float*)alloc(2048 * sizeof(float));
    float* wr    = (float*)alloc(2048 * sizeof(float));
    float* el    = (float*)alloc((size_t)Nn * 8 * sizeof(float));
    float* er    = (float*)alloc((size_t)Nn * 8 * sizeof(float));
    int*   uid   = (int*)alloc((size_t)Nn * sizeof(int));
    int*   unode = (int*)alloc(1024 * sizeof(int));
    int*   cnt   = (int*)alloc(16);
    int*   deg   = (int*)alloc(1024 * sizeof(int));
    int*   off   = (int*)alloc(1025 * sizeof(int));
    int*   fill  = (int*)alloc(1024 * sizeof(int));
    int*   elist = (int*)alloc((size_t)ECAP * sizeof(int));
    float* aval  = (float*)alloc((size_t)ECAP * 8 * sizeof(float));
    float* gemb  = (float*)alloc((size_t)1024 * 512 * sizeof(float));
    // total ws use: ~7.9 MB

    hipLaunchKernelGGL(k_init,    dim3(196),  dim3(256),  0, stream, uid, deg, fill, cnt);
    hipLaunchKernelGGL(k_fold,    dim3(1),    dim3(256),  0, stream, gat_fc_w, attn_l, attn_r, wl, wr);
    hipLaunchKernelGGL(k_eler,    dim3(196),  dim3(256),  0, stream, features, wl, wr, el, er);
    hipLaunchKernelGGL(k_mark,    dim3(4),    dim3(256),  0, stream, url, uid, unode, cnt);
    hipLaunchKernelGGL(k_count,   dim3(1563), dim3(256),  0, stream, dst, uid, deg);
    hipLaunchKernelGGL(k_scan,    dim3(1),    dim3(1024), 0, stream, deg, off);
    hipLaunchKernelGGL(k_scatter, dim3(1563), dim3(256),  0, stream, dst, uid, off, fill, elist);
    hipLaunchKernelGGL(k_soft,    dim3(32),   dim3(256),  0, stream, src, elist, off, el, er, unode, cnt, aval);
    hipLaunchKernelGGL(k_gat,     dim3(1024), dim3(256),  0, stream, features, gat_fc_w, gat_res_w, gat_bias,
                       src, cnt, unode, off, elist, aval, gemb);
    hipLaunchKernelGGL(k_mha,     dim3(1024), dim3(256),  0, stream, url, uid, gemb, ln_g, ln_b,
                       wq, wk, wv, fc_w, fc_b, mha_ln_g, mha_ln_b, out_w, out_b,
                       (float*)d_out);
}

// Round 7
// 387.504 us; speedup vs baseline: 3.7096x; 3.7096x over previous
//
#include <hip/hip_runtime.h>
#include <math.h>

#define Nn 50000
#define Ee 400000
#define FSz 256
#define HD_ 512
#define Bb 1024
#define ECAP 65536
#define SQS 516   // padded row stride for q/k/v/ov in LDS (kills kk*512 bank conflicts)

// World model (settled R5/R6): ALL float inputs fp32; OUTPUT fp32.
static __device__ __forceinline__ int clampi(int v, int lo, int hi){
    return v < lo ? lo : (v > hi ? hi : v);
}

// K0: init workspace (ws is poisoned 0xAA before every launch)
__global__ __launch_bounds__(256) void k_init(int* uid, int* deg, int* fill, int* cnt){
    int i = blockIdx.x * 256 + threadIdx.x;
    if(i < Nn) uid[i] = -1;
    if(i < 1024){ deg[i] = 0; fill[i] = 0; }
    if(i == 0) cnt[0] = 0;
}

// K1: fold attn_l/attn_r into gat_fc_w -> wl,wr [256][8] fp32
__global__ __launch_bounds__(256) void k_fold(const float* __restrict__ W,
                                              const float* __restrict__ al,
                                              const float* __restrict__ ar,
                                              float* __restrict__ wl, float* __restrict__ wr){
    int f = threadIdx.x;
    for(int h = 0; h < 8; h++){
        float sl = 0.f, sr = 0.f;
        for(int d = 0; d < 64; d++){
            float w = W[f*512 + h*64 + d];
            sl += w * al[h*64 + d];
            sr += w * ar[h*64 + d];
        }
        wl[f*8 + h] = sl; wr[f*8 + h] = sr;
    }
}

// K2: el,er for all N nodes. float4 row loads + LDS-staged weights (broadcast reads).
__global__ __launch_bounds__(128) void k_eler(const float* __restrict__ features,
                                              const float* __restrict__ wl, const float* __restrict__ wr,
                                              float* __restrict__ el, float* __restrict__ er){
    __shared__ float swl[2048], swr[2048];
    int t = threadIdx.x;
    for(int i = t; i < 2048; i += 128){ swl[i] = wl[i]; swr[i] = wr[i]; }
    __syncthreads();
    int n = blockIdx.x * 128 + t;
    if(n >= Nn) return;
    const float4* row = (const float4*)(features + (size_t)n * FSz);
    float al[8] = {0,0,0,0,0,0,0,0};
    float ar[8] = {0,0,0,0,0,0,0,0};
    for(int fp = 0; fp < 64; fp += 2){
        float4 v0 = row[fp], v1 = row[fp + 1];
        int f0 = 4*fp;
        #pragma unroll
        for(int h = 0; h < 8; h++){
            al[h] += v0.x*swl[(f0+0)*8+h] + v0.y*swl[(f0+1)*8+h]
                   + v0.z*swl[(f0+2)*8+h] + v0.w*swl[(f0+3)*8+h]
                   + v1.x*swl[(f0+4)*8+h] + v1.y*swl[(f0+5)*8+h]
                   + v1.z*swl[(f0+6)*8+h] + v1.w*swl[(f0+7)*8+h];
            ar[h] += v0.x*swr[(f0+0)*8+h] + v0.y*swr[(f0+1)*8+h]
                   + v0.z*swr[(f0+2)*8+h] + v0.w*swr[(f0+3)*8+h]
                   + v1.x*swr[(f0+4)*8+h] + v1.y*swr[(f0+5)*8+h]
                   + v1.z*swr[(f0+6)*8+h] + v1.w*swr[(f0+7)*8+h];
        }
    }
    #pragma unroll
    for(int h = 0; h < 8; h++){ el[n*8 + h] = al[h]; er[n*8 + h] = ar[h]; }
}

// K3: assign dense ids to unique selected nodes
__global__ __launch_bounds__(256) void k_mark(const int* __restrict__ url, int* uid, int* unode, int* cnt){
    int b = blockIdx.x * 256 + threadIdx.x;
    if(b >= Bb) return;
    int n = clampi(url[b] - 1, 0, Nn - 1);
    int old = atomicCAS(&uid[n], -1, -2);
    if(old == -1){
        int id = atomicAdd(cnt, 1);
        unode[id] = n;
        uid[n] = id;
    }
}

// K4: per-unique-node in-degree
__global__ __launch_bounds__(256) void k_count(const int* __restrict__ dst, const int* __restrict__ uid,
                                               int* __restrict__ deg){
    int e = blockIdx.x * 256 + threadIdx.x;
    if(e >= Ee) return;
    int d = dst[e];
    if((unsigned)d >= (unsigned)Nn) return;
    int u = uid[d];
    if(u >= 0) atomicAdd(&deg[u], 1);
}

// K5: exclusive prefix scan over 1024 degrees -> off[0..1024]
__global__ __launch_bounds__(1024) void k_scan(const int* __restrict__ deg, int* __restrict__ off){
    __shared__ int s[1024];
    int t = threadIdx.x;
    s[t] = deg[t];
    __syncthreads();
    for(int d2 = 1; d2 < 1024; d2 <<= 1){
        int v = (t >= d2) ? s[t - d2] : 0;
        __syncthreads();
        s[t] += v;
        __syncthreads();
    }
    if(t == 0) off[0] = 0;
    off[t + 1] = s[t];
}

// K6: CSR scatter
__global__ __launch_bounds__(256) void k_scatter(const int* __restrict__ dst,
                                                 const int* __restrict__ uid, const int* __restrict__ off,
                                                 int* __restrict__ fill, int* __restrict__ elist){
    int e = blockIdx.x * 256 + threadIdx.x;
    if(e >= Ee) return;
    int d = dst[e];
    if((unsigned)d >= (unsigned)Nn) return;
    int u = uid[d];
    if(u < 0) return;
    int pos = off[u] + atomicAdd(&fill[u], 1);
    if(pos < ECAP) elist[pos] = e;
}

// K6b: per (selected node, head): serial softmax over its edges -> normalized aval
__global__ __launch_bounds__(256) void k_soft(const int* __restrict__ src,
                                              const int* __restrict__ elist, const int* __restrict__ off,
                                              const float* __restrict__ el, const float* __restrict__ er,
                                              const int* __restrict__ unode, const int* __restrict__ cnt,
                                              float* __restrict__ aval){
    int idx = blockIdx.x * 256 + threadIdx.x;
    int u = idx >> 3, h = idx & 7;
    if(u >= cnt[0]) return;
    int n = unode[u];
    float ern = er[n*8 + h];
    int e0 = off[u], e1 = off[u + 1];
    if(e1 > ECAP) e1 = ECAP;
    if(e1 <= e0) return;
    float m = -1e30f;
    for(int ei = e0; ei < e1; ei++){
        int s = clampi(src[elist[ei]], 0, Nn - 1);
        float v = el[s*8 + h] + ern;
        v = v > 0.f ? v : 0.2f * v;
        m = fmaxf(m, v);
    }
    float sum = 0.f;
    for(int ei = e0; ei < e1; ei++){
        int s = clampi(src[elist[ei]], 0, Nn - 1);
        float v = el[s*8 + h] + ern;
        v = v > 0.f ? v : 0.2f * v;
        float w = expf(v - m);
        sum += w;
        aval[(size_t)ei*8 + h] = w;
    }
    float inv = 1.0f / fmaxf(sum, 1e-20f);
    for(int ei = e0; ei < e1; ei++)
        aval[(size_t)ei*8 + h] *= inv;
}

// K7: per unique node: alpha-combine rows, then float2-vectorized unrolled GEMVs.
__global__ __launch_bounds__(256) void k_gat(const float* __restrict__ features,
                                             const float* __restrict__ Wfc,
                                             const float* __restrict__ Wres,
                                             const float* __restrict__ bias,
                                             const int* __restrict__ src,
                                             const int* __restrict__ cnt, const int* __restrict__ unode,
                                             const int* __restrict__ off, const int* __restrict__ elist,
                                             const float* __restrict__ aval,
                                             float* __restrict__ gemb){
    int u = blockIdx.x;
    if(u >= cnt[0]) return;
    int t = threadIdx.x;
    int n = unode[u];

    __shared__ float cxs[8][256];
    __shared__ float fres[256];

    fres[t] = features[(size_t)n * FSz + t];

    float cx[8] = {0,0,0,0,0,0,0,0};
    int e0 = off[u], e1 = off[u + 1];
    if(e1 > ECAP) e1 = ECAP;
    for(int ei = e0; ei < e1; ei++){
        int s = clampi(src[elist[ei]], 0, Nn - 1);
        float x = features[(size_t)s * FSz + t];
        const float* av = &aval[(size_t)ei * 8];    // wave-uniform scalar loads
        #pragma unroll
        for(int h = 0; h < 8; h++) cx[h] += av[h] * x;
    }
    #pragma unroll
    for(int h = 0; h < 8; h++) cxs[h][t] = cx[h];
    __syncthreads();

    // thread owns outputs (2t, 2t+1); h = t>>5 uniform per half-wave
    int h = t >> 5;
    int o0 = 2 * t;
    const float2* Wfc2  = (const float2*)Wfc;     // [256][256] of float2
    const float2* Wres2 = (const float2*)Wres;
    float a0 = 0.f, a1 = 0.f;
    for(int f = 0; f < 256; f += 4){
        float2 w0 = Wfc2[(f+0)*256 + t];
        float2 w1 = Wfc2[(f+1)*256 + t];
        float2 w2 = Wfc2[(f+2)*256 + t];
        float2 w3 = Wfc2[(f+3)*256 + t];
        float2 r0 = Wres2[(f+0)*256 + t];
        float2 r1 = Wres2[(f+1)*256 + t];
        float2 r2 = Wres2[(f+2)*256 + t];
        float2 r3 = Wres2[(f+3)*256 + t];
        float c0 = cxs[h][f+0], c1 = cxs[h][f+1], c2 = cxs[h][f+2], c3 = cxs[h][f+3];
        float x0 = fres[f+0],   x1 = fres[f+1],   x2 = fres[f+2],   x3 = fres[f+3];
        a0 += c0*w0.x + c1*w1.x + c2*w2.x + c3*w3.x + x0*r0.x + x1*r1.x + x2*r2.x + x3*r3.x;
        a1 += c0*w0.y + c1*w1.y + c2*w2.y + c3*w3.y + x0*r0.y + x1*r1.y + x2*r2.y + x3*r3.y;
    }
    float2* gp = (float2*)(gemb + (size_t)u * HD_);
    gp[t] = make_float2(a0 + bias[o0], a1 + bias[o0 + 1]);
}

// K8: per batch element: LN1 -> qkv (register-blocked) -> attn -> fc -> LN2 -> pool -> logits
__global__ __launch_bounds__(256) void k_mha(const int* __restrict__ url, const int* __restrict__ uid,
                                             const float* __restrict__ gemb,
                                             const float* __restrict__ lng, const float* __restrict__ lnb,
                                             const float* __restrict__ wq, const float* __restrict__ wk,
                                             const float* __restrict__ wvp, const float* __restrict__ fcw,
                                             const float* __restrict__ fcb, const float* __restrict__ mlg,
                                             const float* __restrict__ mlb, const float* __restrict__ outw,
                                             const float* __restrict__ outb, float* __restrict__ out){
    __shared__ float A[512];            // xr, later yy
    __shared__ float xnT[64*12];        // LN1 output transposed [d][qq], stride 12 (16B aligned)
    __shared__ float qk[2][8*SQS];      // q,k ; q overlaid by ov after softmax
    __shared__ float vv[8*SQS];
    __shared__ float sc[512];           // [nh][qq][kk]
    __shared__ float mu8[8], rs8[8], pooled[64];

    int b = blockIdx.x, t = threadIdx.x;
    int n = clampi(url[b] - 1, 0, Nn - 1);
    int u = uid[n];
    if(u < 0) u = 0;
    const float* gp = gemb + (size_t)u * HD_;
    A[t] = gp[t]; A[t + 256] = gp[t + 256];
    __syncthreads();
    if(t < 8){
        float s = 0.f, s2 = 0.f;
        for(int d = 0; d < 64; d++){ float v = A[t*64 + d]; s += v; s2 += v * v; }
        float mu = s * (1.0f/64.0f);
        float var = s2 * (1.0f/64.0f) - mu * mu;
        mu8[t] = mu; rs8[t] = rsqrtf(fmaxf(var, 0.0f) + 1e-6f);
    }
    __syncthreads();
    #pragma unroll
    for(int p = 0; p < 2; p++){
        int i = p*256 + t; int q = i >> 6, d = i & 63;
        xnT[d*12 + q] = (A[i] - mu8[q]) * rs8[q] * lng[d] + lnb[d];
    }
    __syncthreads();
    // ---- qkv: thread owns col c; register-block all 8 seq rows per weight load ----
    for(int m3 = 0; m3 < 3; m3++){
        const float* w = (m3 == 0) ? wq : (m3 == 1) ? wk : wvp;
        float* dstm = (m3 == 0) ? &qk[0][0] : (m3 == 1) ? &qk[1][0] : vv;
        #pragma unroll
        for(int p = 0; p < 2; p++){
            int c = p*256 + t;
            float acc[8] = {0,0,0,0,0,0,0,0};
            for(int d = 0; d < 64; d += 4){
                float w0 = w[(d+0)*512 + c];
                float w1 = w[(d+1)*512 + c];
                float w2 = w[(d+2)*512 + c];
                float w3 = w[(d+3)*512 + c];
                const float4* x0p = (const float4*)&xnT[(d+0)*12];
                const float4* x1p = (const float4*)&xnT[(d+1)*12];
                const float4* x2p = (const float4*)&xnT[(d+2)*12];
                const float4* x3p = (const float4*)&xnT[(d+3)*12];
                float4 xa0 = x0p[0], xb0 = x0p[1];
                float4 xa1 = x1p[0], xb1 = x1p[1];
                float4 xa2 = x2p[0], xb2 = x2p[1];
                float4 xa3 = x3p[0], xb3 = x3p[1];
                acc[0] += xa0.x*w0 + xa1.x*w1 + xa2.x*w2 + xa3.x*w3;
                acc[1] += xa0.y*w0 + xa1.y*w1 + xa2.y*w2 + xa3.y*w3;
                acc[2] += xa0.z*w0 + xa1.z*w1 + xa2.z*w2 + xa3.z*w3;
                acc[3] += xa0.w*w0 + xa1.w*w1 + xa2.w*w2 + xa3.w*w3;
                acc[4] += xb0.x*w0 + xb1.x*w1 + xb2.x*w2 + xb3.x*w3;
                acc[5] += xb0.y*w0 + xb1.y*w1 + xb2.y*w2 + xb3.y*w3;
                acc[6] += xb0.z*w0 + xb1.z*w1 + xb2.z*w2 + xb3.z*w3;
                acc[7] += xb0.w*w0 + xb1.w*w1 + xb2.w*w2 + xb3.w*w3;
            }
            #pragma unroll
            for(int qq = 0; qq < 8; qq++) dstm[qq*SQS + c] = acc[qq];
        }
    }
    __syncthreads();
    // ---- scores sc[nh*64 + qq*8 + kk] ----
    #pragma unroll
    for(int p = 0; p < 2; p++){
        int idx = p*256 + t;
        int nh = idx >> 6, qq = (idx >> 3) & 7, kk = idx & 7;
        const float* qrow = &qk[0][qq*SQS + nh*64];
        const float* krow = &qk[1][kk*SQS + nh*64];
        float s = 0.f;
        for(int d = 0; d < 64; d++) s += qrow[d] * krow[d];
        sc[idx] = s * 0.125f;
    }
    __syncthreads();
    if(t < 64){
        float mx = -1e30f;
        #pragma unroll
        for(int k = 0; k < 8; k++) mx = fmaxf(mx, sc[t*8 + k]);
        float e[8]; float s = 0.f;
        #pragma unroll
        for(int k = 0; k < 8; k++){ e[k] = expf(sc[t*8 + k] - mx); s += e[k]; }
        float inv = 1.0f / s;
        #pragma unroll
        for(int k = 0; k < 8; k++) sc[t*8 + k] = e[k] * inv;
    }
    __syncthreads();
    // ---- attn @ v -> overlay into qk[0] (q dead) ----
    {
        float* ov = &qk[0][0];
        #pragma unroll
        for(int p = 0; p < 16; p++){
            int idx = p*256 + t;
            int qq = idx >> 9, o = idx & 511, nh = o >> 6;
            float s = 0.f;
            #pragma unroll
            for(int kk = 0; kk < 8; kk++) s += sc[nh*64 + qq*8 + kk] * vv[kk*SQS + o];
            ov[qq*SQS + o] = s;
        }
    }
    __syncthreads();
    // ---- fc + bias + residual: thread = (qq = t>>5, dd pair = 2*(t&31)) ----
    {
        const float* ov = &qk[0][0];
        int g = t & 31, qq = t >> 5;
        int dd0 = 2 * g;
        const float* orow = ov + qq*SQS;
        const float2* fw2 = (const float2*)fcw;       // [512][32] float2
        float a0 = 0.f, a1 = 0.f;
        for(int k = 0; k < 512; k += 4){
            float2 f0 = fw2[(k+0)*32 + g];
            float2 f1 = fw2[(k+1)*32 + g];
            float2 f2 = fw2[(k+2)*32 + g];
            float2 f3 = fw2[(k+3)*32 + g];
            float x0 = orow[k+0], x1 = orow[k+1], x2 = orow[k+2], x3 = orow[k+3];
            a0 += x0*f0.x + x1*f1.x + x2*f2.x + x3*f3.x;
            a1 += x0*f0.y + x1*f1.y + x2*f2.y + x3*f3.y;
        }
        // residual: xn[qq*64+dd] lives at xnT[dd*12+qq]
        A[qq*64 + dd0]     = a0 + fcb[dd0]     + xnT[(dd0)*12 + qq];
        A[qq*64 + dd0 + 1] = a1 + fcb[dd0 + 1] + xnT[(dd0+1)*12 + qq];
    }
    __syncthreads();
    if(t < 8){
        float s = 0.f, s2 = 0.f;
        for(int d = 0; d < 64; d++){ float v = A[t*64 + d]; s += v; s2 += v * v; }
        float mu = s * (1.0f/64.0f);
        float var = s2 * (1.0f/64.0f) - mu * mu;
        mu8[t] = mu; rs8[t] = rsqrtf(fmaxf(var, 0.0f) + 1e-6f);
    }
    __syncthreads();
    if(t < 64){
        float g2 = mlg[t], bb = mlb[t];
        float s = 0.f;
        #pragma unroll
        for(int qq = 0; qq < 8; qq++)
            s += (A[qq*64 + t] - mu8[qq]) * rs8[qq] * g2 + bb;
        pooled[t] = s;
    }
    __syncthreads();
    if(t < 2){
        float s = outb[t];
        for(int d = 0; d < 64; d++) s += pooled[d] * outw[d*2 + t];
        out[b*2 + t] = s;
    }
}

extern "C" void kernel_launch(void* const* d_in, const int* in_sizes, int n_in,
                              void* d_out, int out_size, void* d_ws, size_t ws_size,
                              hipStream_t stream){
    (void)in_sizes; (void)n_in; (void)out_size; (void)ws_size;
    const float* features  = (const float*)d_in[0];
    const int*   src       = (const int*)d_in[1];
    const int*   dst       = (const int*)d_in[2];
    const int*   url       = (const int*)d_in[3];
    const float* gat_fc_w  = (const float*)d_in[4];
    const float* attn_l    = (const float*)d_in[5];
    const float* attn_r    = (const float*)d_in[6];
    const float* gat_res_w = (const float*)d_in[7];
    const float* gat_bias  = (const float*)d_in[8];
    const float* ln_g      = (const float*)d_in[9];
    const float* ln_b      = (const float*)d_in[10];
    const float* wq        = (const float*)d_in[11];
    const float* wk        = (const float*)d_in[12];
    const float* wv        = (const float*)d_in[13];
    const float* fc_w      = (const float*)d_in[14];
    const float* fc_b      = (const float*)d_in[15];
    const float* mha_ln_g  = (const float*)d_in[16];
    const float* mha_ln_b  = (const float*)d_in[17];
    const float* out_w     = (const float*)d_in[18];
    const float* out_b     = (const float*)d_in[19];

    char* base = (char*)d_ws;
    size_t cur = 0;
    auto alloc = [&](size_t nbytes) -> void* {
        void* p = base + cur;
        cur = (cur + nbytes + 255) & ~(size_t)255;
        return p;
    };
    float* wl    = (float*)alloc(2048 * sizeof(float));
    float* wr    = (float*)alloc(2048 * sizeof(float));
    float* el    = (float*)alloc((size_t)Nn * 8 * sizeof(float));
    float* er    = (float*)alloc((size_t)Nn * 8 * sizeof(float));
    int*   uid   = (int*)alloc((size_t)Nn * sizeof(int));
    int*   unode = (int*)alloc(1024 * sizeof(int));
    int*   cnt   = (int*)alloc(16);
    int*   deg   = (int*)alloc(1024 * sizeof(int));
    int*   off   = (int*)alloc(1025 * sizeof(int));
    int*   fill  = (int*)alloc(1024 * sizeof(int));
    int*   elist = (int*)alloc((size_t)ECAP * sizeof(int));
    float* aval  = (float*)alloc((size_t)ECAP * 8 * sizeof(float));
    float* gemb  = (float*)alloc((size_t)1024 * 512 * sizeof(float));

    hipLaunchKernelGGL(k_init,    dim3(196),  dim3(256),  0, stream, uid, deg, fill, cnt);
    hipLaunchKernelGGL(k_fold,    dim3(1),    dim3(256),  0, stream, gat_fc_w, attn_l, attn_r, wl, wr);
    hipLaunchKernelGGL(k_eler,    dim3(391),  dim3(128),  0, stream, features, wl, wr, el, er);
    hipLaunchKernelGGL(k_mark,    dim3(4),    dim3(256),  0, stream, url, uid, unode, cnt);
    hipLaunchKernelGGL(k_count,   dim3(1563), dim3(256),  0, stream, dst, uid, deg);
    hipLaunchKernelGGL(k_scan,    dim3(1),    dim3(1024), 0, stream, deg, off);
    hipLaunchKernelGGL(k_scatter, dim3(1563), dim3(256),  0, stream, dst, uid, off, fill, elist);
    hipLaunchKernelGGL(k_soft,    dim3(32),   dim3(256),  0, stream, src, elist, off, el, er, unode, cnt, aval);
    hipLaunchKernelGGL(k_gat,     dim3(1024), dim3(256),  0, stream, features, gat_fc_w, gat_res_w, gat_bias,
                       src, cnt, unode, off, elist, aval, gemb);
    hipLaunchKernelGGL(k_mha,     dim3(1024), dim3(256),  0, stream, url, uid, gemb, ln_g, ln_b,
                       wq, wk, wv, fc_w, fc_b, mha_ln_g, mha_ln_b, out_w, out_b,
                       (float*)d_out);
}

// Round 8
// 335.093 us; speedup vs baseline: 4.2897x; 1.1564x over previous
//
#include <hip/hip_runtime.h>
#include <math.h>

#define Nn 50000
#define Ee 400000
#define FSz 256
#define HD_ 512
#define Bb 1024
#define ECAP 65536
#define SQS 516   // padded row stride for q/k/v/ov in LDS (8 rows land on 8 distinct banks)

// World model (settled R5/R6): ALL float inputs fp32; OUTPUT fp32.
static __device__ __forceinline__ int clampi(int v, int lo, int hi){
    return v < lo ? lo : (v > hi ? hi : v);
}

// K0: init workspace (ws is poisoned 0xAA before every launch)
__global__ __launch_bounds__(256) void k_init(int* uid, int* deg, int* fill, int* cnt){
    int i = blockIdx.x * 256 + threadIdx.x;
    if(i < Nn) uid[i] = -1;
    if(i < 1024){ deg[i] = 0; fill[i] = 0; }
    if(i == 0) cnt[0] = 0;
}

// K1: fold attn_l/attn_r into gat_fc_w -> wl,wr [256][8] fp32
__global__ __launch_bounds__(256) void k_fold(const float* __restrict__ W,
                                              const float* __restrict__ al,
                                              const float* __restrict__ ar,
                                              float* __restrict__ wl, float* __restrict__ wr){
    __shared__ float sal[512], sar[512];
    int t = threadIdx.x;
    sal[t] = al[t]; sal[t+256] = al[t+256];
    sar[t] = ar[t]; sar[t+256] = ar[t+256];
    __syncthreads();
    const float4* Wr = (const float4*)(W + t*512);
    float accl[8] = {0,0,0,0,0,0,0,0};
    float accr[8] = {0,0,0,0,0,0,0,0};
    for(int i = 0; i < 128; i++){
        float4 w = Wr[i];
        int o = 4*i;               // o = h*64 + d
        int h = o >> 6;
        const float* alp = &sal[o];
        const float* arp = &sar[o];
        accl[h] += w.x*alp[0] + w.y*alp[1] + w.z*alp[2] + w.w*alp[3];
        accr[h] += w.x*arp[0] + w.y*arp[1] + w.z*arp[2] + w.w*arp[3];
    }
    #pragma unroll
    for(int h = 0; h < 8; h++){ wl[t*8 + h] = accl[h]; wr[t*8 + h] = accr[h]; }
}

// K2: el,er for all N nodes. float4 row loads + LDS-staged weights (broadcast reads).
__global__ __launch_bounds__(128) void k_eler(const float* __restrict__ features,
                                              const float* __restrict__ wl, const float* __restrict__ wr,
                                              float* __restrict__ el, float* __restrict__ er){
    __shared__ float swl[2048], swr[2048];
    int t = threadIdx.x;
    for(int i = t; i < 2048; i += 128){ swl[i] = wl[i]; swr[i] = wr[i]; }
    __syncthreads();
    int n = blockIdx.x * 128 + t;
    if(n >= Nn) return;
    const float4* row = (const float4*)(features + (size_t)n * FSz);
    float al[8] = {0,0,0,0,0,0,0,0};
    float ar[8] = {0,0,0,0,0,0,0,0};
    for(int fp = 0; fp < 64; fp += 2){
        float4 v0 = row[fp], v1 = row[fp + 1];
        int f0 = 4*fp;
        #pragma unroll
        for(int h = 0; h < 8; h++){
            al[h] += v0.x*swl[(f0+0)*8+h] + v0.y*swl[(f0+1)*8+h]
                   + v0.z*swl[(f0+2)*8+h] + v0.w*swl[(f0+3)*8+h]
                   + v1.x*swl[(f0+4)*8+h] + v1.y*swl[(f0+5)*8+h]
                   + v1.z*swl[(f0+6)*8+h] + v1.w*swl[(f0+7)*8+h];
            ar[h] += v0.x*swr[(f0+0)*8+h] + v0.y*swr[(f0+1)*8+h]
                   + v0.z*swr[(f0+2)*8+h] + v0.w*swr[(f0+3)*8+h]
                   + v1.x*swr[(f0+4)*8+h] + v1.y*swr[(f0+5)*8+h]
                   + v1.z*swr[(f0+6)*8+h] + v1.w*swr[(f0+7)*8+h];
        }
    }
    #pragma unroll
    for(int h = 0; h < 8; h++){ el[n*8 + h] = al[h]; er[n*8 + h] = ar[h]; }
}

// K3: assign dense ids to unique selected nodes
__global__ __launch_bounds__(256) void k_mark(const int* __restrict__ url, int* uid, int* unode, int* cnt){
    int b = blockIdx.x * 256 + threadIdx.x;
    if(b >= Bb) return;
    int n = clampi(url[b] - 1, 0, Nn - 1);
    int old = atomicCAS(&uid[n], -1, -2);
    if(old == -1){
        int id = atomicAdd(cnt, 1);
        unode[id] = n;
        uid[n] = id;
    }
}

// K4: per-unique-node in-degree
__global__ __launch_bounds__(256) void k_count(const int* __restrict__ dst, const int* __restrict__ uid,
                                               int* __restrict__ deg){
    int e = blockIdx.x * 256 + threadIdx.x;
    if(e >= Ee) return;
    int d = dst[e];
    if((unsigned)d >= (unsigned)Nn) return;
    int u = uid[d];
    if(u >= 0) atomicAdd(&deg[u], 1);
}

// K5: exclusive prefix scan over 1024 degrees -> off[0..1024]
__global__ __launch_bounds__(1024) void k_scan(const int* __restrict__ deg, int* __restrict__ off){
    __shared__ int s[1024];
    int t = threadIdx.x;
    s[t] = deg[t];
    __syncthreads();
    for(int d2 = 1; d2 < 1024; d2 <<= 1){
        int v = (t >= d2) ? s[t - d2] : 0;
        __syncthreads();
        s[t] += v;
        __syncthreads();
    }
    if(t == 0) off[0] = 0;
    off[t + 1] = s[t];
}

// K6: CSR scatter
__global__ __launch_bounds__(256) void k_scatter(const int* __restrict__ dst,
                                                 const int* __restrict__ uid, const int* __restrict__ off,
                                                 int* __restrict__ fill, int* __restrict__ elist){
    int e = blockIdx.x * 256 + threadIdx.x;
    if(e >= Ee) return;
    int d = dst[e];
    if((unsigned)d >= (unsigned)Nn) return;
    int u = uid[d];
    if(u < 0) return;
    int pos = off[u] + atomicAdd(&fill[u], 1);
    if(pos < ECAP) elist[pos] = e;
}

// K6b: per (selected node, head): serial softmax over its edges -> normalized aval
__global__ __launch_bounds__(256) void k_soft(const int* __restrict__ src,
                                              const int* __restrict__ elist, const int* __restrict__ off,
                                              const float* __restrict__ el, const float* __restrict__ er,
                                              const int* __restrict__ unode, const int* __restrict__ cnt,
                                              float* __restrict__ aval){
    int idx = blockIdx.x * 256 + threadIdx.x;
    int u = idx >> 3, h = idx & 7;
    if(u >= cnt[0]) return;
    int n = unode[u];
    float ern = er[n*8 + h];
    int e0 = off[u], e1 = off[u + 1];
    if(e1 > ECAP) e1 = ECAP;
    if(e1 <= e0) return;
    float m = -1e30f;
    for(int ei = e0; ei < e1; ei++){
        int s = clampi(src[elist[ei]], 0, Nn - 1);
        float v = el[s*8 + h] + ern;
        v = v > 0.f ? v : 0.2f * v;
        m = fmaxf(m, v);
    }
    float sum = 0.f;
    for(int ei = e0; ei < e1; ei++){
        int s = clampi(src[elist[ei]], 0, Nn - 1);
        float v = el[s*8 + h] + ern;
        v = v > 0.f ? v : 0.2f * v;
        float w = expf(v - m);
        sum += w;
        aval[(size_t)ei*8 + h] = w;
    }
    float inv = 1.0f / fmaxf(sum, 1e-20f);
    for(int ei = e0; ei < e1; ei++)
        aval[(size_t)ei*8 + h] *= inv;
}

// K7: TWO nodes per block (halves per-CU L2 weight traffic — the binding constraint).
__global__ __launch_bounds__(256) void k_gat(const float* __restrict__ features,
                                             const float* __restrict__ Wfc,
                                             const float* __restrict__ Wres,
                                             const float* __restrict__ bias,
                                             const int* __restrict__ src,
                                             const int* __restrict__ cnt, const int* __restrict__ unode,
                                             const int* __restrict__ off, const int* __restrict__ elist,
                                             const float* __restrict__ aval,
                                             float* __restrict__ gemb){
    int t = threadIdx.x;
    int cntv = cnt[0];
    int u0 = blockIdx.x * 2;
    if(u0 >= cntv) return;

    __shared__ float cxs[2][8][256];   // 16 KB
    __shared__ float fres[2][256];     //  2 KB

    #pragma unroll
    for(int j = 0; j < 2; j++){
        int u = u0 + j;
        if(u < cntv){
            int n = unode[u];
            fres[j][t] = features[(size_t)n * FSz + t];
            float cx[8] = {0,0,0,0,0,0,0,0};
            int e0 = off[u], e1 = off[u + 1];
            if(e1 > ECAP) e1 = ECAP;
            for(int ei = e0; ei < e1; ei++){
                int s = clampi(src[elist[ei]], 0, Nn - 1);
                float x = features[(size_t)s * FSz + t];
                const float* av = &aval[(size_t)ei * 8];   // wave-uniform
                #pragma unroll
                for(int h = 0; h < 8; h++) cx[h] += av[h] * x;
            }
            #pragma unroll
            for(int h = 0; h < 8; h++) cxs[j][h][t] = cx[h];
        } else {
            fres[j][t] = 0.f;
            #pragma unroll
            for(int h = 0; h < 8; h++) cxs[j][h][t] = 0.f;
        }
    }
    __syncthreads();

    // thread owns output cols (2t, 2t+1); h = t>>5 is half-wave-uniform
    int h = t >> 5;
    int o0 = 2 * t;
    const float2* Wfc2  = (const float2*)Wfc;     // [256][256] of float2
    const float2* Wres2 = (const float2*)Wres;
    float a00 = 0.f, a01 = 0.f, a10 = 0.f, a11 = 0.f;
    for(int f = 0; f < 256; f += 4){
        float2 w0 = Wfc2[(f+0)*256 + t];
        float2 w1 = Wfc2[(f+1)*256 + t];
        float2 w2 = Wfc2[(f+2)*256 + t];
        float2 w3 = Wfc2[(f+3)*256 + t];
        float2 r0 = Wres2[(f+0)*256 + t];
        float2 r1 = Wres2[(f+1)*256 + t];
        float2 r2 = Wres2[(f+2)*256 + t];
        float2 r3 = Wres2[(f+3)*256 + t];
        {   // node 0
            float c0 = cxs[0][h][f+0], c1 = cxs[0][h][f+1], c2 = cxs[0][h][f+2], c3 = cxs[0][h][f+3];
            float x0 = fres[0][f+0],   x1 = fres[0][f+1],   x2 = fres[0][f+2],   x3 = fres[0][f+3];
            a00 += c0*w0.x + c1*w1.x + c2*w2.x + c3*w3.x + x0*r0.x + x1*r1.x + x2*r2.x + x3*r3.x;
            a01 += c0*w0.y + c1*w1.y + c2*w2.y + c3*w3.y + x0*r0.y + x1*r1.y + x2*r2.y + x3*r3.y;
        }
        {   // node 1
            float c0 = cxs[1][h][f+0], c1 = cxs[1][h][f+1], c2 = cxs[1][h][f+2], c3 = cxs[1][h][f+3];
            float x0 = fres[1][f+0],   x1 = fres[1][f+1],   x2 = fres[1][f+2],   x3 = fres[1][f+3];
            a10 += c0*w0.x + c1*w1.x + c2*w2.x + c3*w3.x + x0*r0.x + x1*r1.x + x2*r2.x + x3*r3.x;
            a11 += c0*w0.y + c1*w1.y + c2*w2.y + c3*w3.y + x0*r0.y + x1*r1.y + x2*r2.y + x3*r3.y;
        }
    }
    float b0 = bias[o0], b1 = bias[o0 + 1];
    {
        float2* gp = (float2*)(gemb + (size_t)(u0) * HD_);
        gp[t] = make_float2(a00 + b0, a01 + b1);
    }
    if(u0 + 1 < cntv){
        float2* gp = (float2*)(gemb + (size_t)(u0 + 1) * HD_);
        gp[t] = make_float2(a10 + b0, a11 + b1);
    }
}

// K8: per batch element. LDS 38.5KB -> 4 blocks/CU. v computed after scores
// (overwrites dead q); ov overwrites dead k; sc aliases dead xr buffer.
__global__ __launch_bounds__(256) void k_mha(const int* __restrict__ url, const int* __restrict__ uid,
                                             const float* __restrict__ gemb,
                                             const float* __restrict__ lng, const float* __restrict__ lnb,
                                             const float* __restrict__ wq, const float* __restrict__ wk,
                                             const float* __restrict__ wvp, const float* __restrict__ fcw,
                                             const float* __restrict__ fcb, const float* __restrict__ mlg,
                                             const float* __restrict__ mlb, const float* __restrict__ outw,
                                             const float* __restrict__ outb, float* __restrict__ out){
    __shared__ float A[512];            // xr -> sc (scores) -> yy
    __shared__ float xnT[64*12];        // LN1 output transposed [d][qq], stride 12
    __shared__ float qk[2][8*SQS];      // q,k ; later v->qk[0], ov->qk[1]
    __shared__ float mu8[8], rs8[8], pooled[64];
    float* sc = A;                      // alias: xr dead before scores, yy written after sc dead

    int b = blockIdx.x, t = threadIdx.x;
    int n = clampi(url[b] - 1, 0, Nn - 1);
    int u = uid[n];
    if(u < 0) u = 0;
    const float* gp = gemb + (size_t)u * HD_;
    A[t] = gp[t]; A[t + 256] = gp[t + 256];
    __syncthreads();
    if(t < 8){
        float s = 0.f, s2 = 0.f;
        for(int d = 0; d < 64; d++){ float v = A[t*64 + d]; s += v; s2 += v * v; }
        float mu = s * (1.0f/64.0f);
        float var = s2 * (1.0f/64.0f) - mu * mu;
        mu8[t] = mu; rs8[t] = rsqrtf(fmaxf(var, 0.0f) + 1e-6f);
    }
    __syncthreads();
    #pragma unroll
    for(int p = 0; p < 2; p++){
        int i = p*256 + t; int q = i >> 6, d = i & 63;
        xnT[d*12 + q] = (A[i] - mu8[q]) * rs8[q] * lng[d] + lnb[d];
    }
    __syncthreads();
    // ---- q and k projections: thread owns cols t and t+256; 8 loads in flight ----
    #pragma unroll
    for(int m3 = 0; m3 < 2; m3++){
        const float* w = (m3 == 0) ? wq : wk;
        float* dstm = &qk[m3][0];
        float a0[8] = {0,0,0,0,0,0,0,0};
        float a1[8] = {0,0,0,0,0,0,0,0};
        for(int d = 0; d < 64; d += 4){
            float w00 = w[(d+0)*512 + t], w01 = w[(d+0)*512 + t + 256];
            float w10 = w[(d+1)*512 + t], w11 = w[(d+1)*512 + t + 256];
            float w20 = w[(d+2)*512 + t], w21 = w[(d+2)*512 + t + 256];
            float w30 = w[(d+3)*512 + t], w31 = w[(d+3)*512 + t + 256];
            const float4* x0p = (const float4*)&xnT[(d+0)*12];
            const float4* x1p = (const float4*)&xnT[(d+1)*12];
            const float4* x2p = (const float4*)&xnT[(d+2)*12];
            const float4* x3p = (const float4*)&xnT[(d+3)*12];
            float4 xa0 = x0p[0], xb0 = x0p[1];
            float4 xa1 = x1p[0], xb1 = x1p[1];
            float4 xa2 = x2p[0], xb2 = x2p[1];
            float4 xa3 = x3p[0], xb3 = x3p[1];
            a0[0] += xa0.x*w00 + xa1.x*w10 + xa2.x*w20 + xa3.x*w30;
            a1[0] += xa0.x*w01 + xa1.x*w11 + xa2.x*w21 + xa3.x*w31;
            a0[1] += xa0.y*w00 + xa1.y*w10 + xa2.y*w20 + xa3.y*w30;
            a1[1] += xa0.y*w01 + xa1.y*w11 + xa2.y*w21 + xa3.y*w31;
            a0[2] += xa0.z*w00 + xa1.z*w10 + xa2.z*w20 + xa3.z*w30;
            a1[2] += xa0.z*w01 + xa1.z*w11 + xa2.z*w21 + xa3.z*w31;
            a0[3] += xa0.w*w00 + xa1.w*w10 + xa2.w*w20 + xa3.w*w30;
            a1[3] += xa0.w*w01 + xa1.w*w11 + xa2.w*w21 + xa3.w*w31;
            a0[4] += xb0.x*w00 + xb1.x*w10 + xb2.x*w20 + xb3.x*w30;
            a1[4] += xb0.x*w01 + xb1.x*w11 + xb2.x*w21 + xb3.x*w31;
            a0[5] += xb0.y*w00 + xb1.y*w10 + xb2.y*w20 + xb3.y*w30;
            a1[5] += xb0.y*w01 + xb1.y*w11 + xb2.y*w21 + xb3.y*w31;
            a0[6] += xb0.z*w00 + xb1.z*w10 + xb2.z*w20 + xb3.z*w30;
            a1[6] += xb0.z*w01 + xb1.z*w11 + xb2.z*w21 + xb3.z*w31;
            a0[7] += xb0.w*w00 + xb1.w*w10 + xb2.w*w20 + xb3.w*w30;
            a1[7] += xb0.w*w01 + xb1.w*w11 + xb2.w*w21 + xb3.w*w31;
        }
        #pragma unroll
        for(int qq = 0; qq < 8; qq++){
            dstm[qq*SQS + t]       = a0[qq];
            dstm[qq*SQS + t + 256] = a1[qq];
        }
    }
    __syncthreads();
    // ---- scores sc[nh*64 + qq*8 + kk] (A/xr is dead; sc aliases it) ----
    #pragma unroll
    for(int p = 0; p < 2; p++){
        int idx = p*256 + t;
        int nh = idx >> 6, qq = (idx >> 3) & 7, kk = idx & 7;
        const float* qrow = &qk[0][qq*SQS + nh*64];
        const float* krow = &qk[1][kk*SQS + nh*64];
        float s = 0.f;
        for(int d = 0; d < 64; d++) s += qrow[d] * krow[d];
        sc[idx] = s * 0.125f;
    }
    __syncthreads();
    if(t < 64){
        float mx = -1e30f;
        #pragma unroll
        for(int k = 0; k < 8; k++) mx = fmaxf(mx, sc[t*8 + k]);
        float e[8]; float s = 0.f;
        #pragma unroll
        for(int k = 0; k < 8; k++){ e[k] = expf(sc[t*8 + k] - mx); s += e[k]; }
        float inv = 1.0f / s;
        #pragma unroll
        for(int k = 0; k < 8; k++) sc[t*8 + k] = e[k] * inv;
    }
    __syncthreads();
    // ---- v projection into qk[0] (q dead after scores) ----
    {
        const float* w = wvp;
        float* dstm = &qk[0][0];
        float a0[8] = {0,0,0,0,0,0,0,0};
        float a1[8] = {0,0,0,0,0,0,0,0};
        for(int d = 0; d < 64; d += 4){
            float w00 = w[(d+0)*512 + t], w01 = w[(d+0)*512 + t + 256];
            float w10 = w[(d+1)*512 + t], w11 = w[(d+1)*512 + t + 256];
            float w20 = w[(d+2)*512 + t], w21 = w[(d+2)*512 + t + 256];
            float w30 = w[(d+3)*512 + t], w31 = w[(d+3)*512 + t + 256];
            const float4* x0p = (const float4*)&xnT[(d+0)*12];
            const float4* x1p = (const float4*)&xnT[(d+1)*12];
            const float4* x2p = (const float4*)&xnT[(d+2)*12];
            const float4* x3p = (const float4*)&xnT[(d+3)*12];
            float4 xa0 = x0p[0], xb0 = x0p[1];
            float4 xa1 = x1p[0], xb1 = x1p[1];
            float4 xa2 = x2p[0], xb2 = x2p[1];
            float4 xa3 = x3p[0], xb3 = x3p[1];
            a0[0] += xa0.x*w00 + xa1.x*w10 + xa2.x*w20 + xa3.x*w30;
            a1[0] += xa0.x*w01 + xa1.x*w11 + xa2.x*w21 + xa3.x*w31;
            a0[1] += xa0.y*w00 + xa1.y*w10 + xa2.y*w20 + xa3.y*w30;
            a1[1] += xa0.y*w01 + xa1.y*w11 + xa2.y*w21 + xa3.y*w31;
            a0[2] += xa0.z*w00 + xa1.z*w10 + xa2.z*w20 + xa3.z*w30;
            a1[2] += xa0.z*w01 + xa1.z*w11 + xa2.z*w21 + xa3.z*w31;
            a0[3] += xa0.w*w00 + xa1.w*w10 + xa2.w*w20 + xa3.w*w30;
            a1[3] += xa0.w*w01 + xa1.w*w11 + xa2.w*w21 + xa3.w*w31;
            a0[4] += xb0.x*w00 + xb1.x*w10 + xb2.x*w20 + xb3.x*w30;
            a1[4] += xb0.x*w01 + xb1.x*w11 + xb2.x*w21 + xb3.x*w31;
            a0[5] += xb0.y*w00 + xb1.y*w10 + xb2.y*w20 + xb3.y*w30;
            a1[5] += xb0.y*w01 + xb1.y*w11 + xb2.y*w21 + xb3.y*w31;
            a0[6] += xb0.z*w00 + xb1.z*w10 + xb2.z*w20 + xb3.z*w30;
            a1[6] += xb0.z*w01 + xb1.z*w11 + xb2.z*w21 + xb3.z*w31;
            a0[7] += xb0.w*w00 + xb1.w*w10 + xb2.w*w20 + xb3.w*w30;
            a1[7] += xb0.w*w01 + xb1.w*w11 + xb2.w*w21 + xb3.w*w31;
        }
        #pragma unroll
        for(int qq = 0; qq < 8; qq++){
            dstm[qq*SQS + t]       = a0[qq];
            dstm[qq*SQS + t + 256] = a1[qq];
        }
    }
    __syncthreads();
    // ---- attn @ v -> ov into qk[1] (k dead) ----
    #pragma unroll
    for(int p = 0; p < 16; p++){
        int idx = p*256 + t;
        int qq = idx >> 9, o = idx & 511, nh = o >> 6;
        float s = 0.f;
        #pragma unroll
        for(int kk = 0; kk < 8; kk++) s += sc[nh*64 + qq*8 + kk] * qk[0][kk*SQS + o];
        qk[1][qq*SQS + o] = s;
    }
    __syncthreads();
    // ---- fc + bias + residual -> A (sc dead) ----
    {
        int g = t & 31, qq = t >> 5;
        int dd0 = 2 * g;
        const float* orow = &qk[1][qq*SQS];
        const float2* fw2 = (const float2*)fcw;       // [512][32] float2
        float a0 = 0.f, a1 = 0.f;
        for(int k = 0; k < 512; k += 4){
            float2 f0 = fw2[(k+0)*32 + g];
            float2 f1 = fw2[(k+1)*32 + g];
            float2 f2 = fw2[(k+2)*32 + g];
            float2 f3 = fw2[(k+3)*32 + g];
            float x0 = orow[k+0], x1 = orow[k+1], x2 = orow[k+2], x3 = orow[k+3];
            a0 += x0*f0.x + x1*f1.x + x2*f2.x + x3*f3.x;
            a1 += x0*f0.y + x1*f1.y + x2*f2.y + x3*f3.y;
        }
        float y0 = a0 + fcb[dd0]     + xnT[(dd0)*12 + qq];
        float y1 = a1 + fcb[dd0 + 1] + xnT[(dd0+1)*12 + qq];
        __syncthreads();               // all sc reads (attn) done before A overwrite
        A[qq*64 + dd0]     = y0;
        A[qq*64 + dd0 + 1] = y1;
    }
    __syncthreads();
    if(t < 8){
        float s = 0.f, s2 = 0.f;
        for(int d = 0; d < 64; d++){ float v = A[t*64 + d]; s += v; s2 += v * v; }
        float mu = s * (1.0f/64.0f);
        float var = s2 * (1.0f/64.0f) - mu * mu;
        mu8[t] = mu; rs8[t] = rsqrtf(fmaxf(var, 0.0f) + 1e-6f);
    }
    __syncthreads();
    if(t < 64){
        float g2 = mlg[t], bb = mlb[t];
        float s = 0.f;
        #pragma unroll
        for(int qq = 0; qq < 8; qq++)
            s += (A[qq*64 + t] - mu8[qq]) * rs8[qq] * g2 + bb;
        pooled[t] = s;
    }
    __syncthreads();
    if(t < 2){
        float s = outb[t];
        for(int d = 0; d < 64; d++) s += pooled[d] * outw[d*2 + t];
        out[b*2 + t] = s;
    }
}

extern "C" void kernel_launch(void* const* d_in, const int* in_sizes, int n_in,
                              void* d_out, int out_size, void* d_ws, size_t ws_size,
                              hipStream_t stream){
    (void)in_sizes; (void)n_in; (void)out_size; (void)ws_size;
    const float* features  = (const float*)d_in[0];
    const int*   src       = (const int*)d_in[1];
    const int*   dst       = (const int*)d_in[2];
    const int*   url       = (const int*)d_in[3];
    const float* gat_fc_w  = (const float*)d_in[4];
    const float* attn_l    = (const float*)d_in[5];
    const float* attn_r    = (const float*)d_in[6];
    const float* gat_res_w = (const float*)d_in[7];
    const float* gat_bias  = (const float*)d_in[8];
    const float* ln_g      = (const float*)d_in[9];
    const float* ln_b      = (const float*)d_in[10];
    const float* wq        = (const float*)d_in[11];
    const float* wk        = (const float*)d_in[12];
    const float* wv        = (const float*)d_in[13];
    const float* fc_w      = (const float*)d_in[14];
    const float* fc_b      = (const float*)d_in[15];
    const float* mha_ln_g  = (const float*)d_in[16];
    const float* mha_ln_b  = (const float*)d_in[17];
    const float* out_w     = (const float*)d_in[18];
    const float* out_b     = (const float*)d_in[19];

    char* base = (char*)d_ws;
    size_t cur = 0;
    auto alloc = [&](size_t nbytes) -> void* {
        void* p = base + cur;
        cur = (cur + nbytes + 255) & ~(size_t)255;
        return p;
    };
    float* wl    = (float*)alloc(2048 * sizeof(float));
    float* wr    = (float*)alloc(2048 * sizeof(float));
    float* el    = (float*)alloc((size_t)Nn * 8 * sizeof(float));
    float* er    = (float*)alloc((size_t)Nn * 8 * sizeof(float));
    int*   uid   = (int*)alloc((size_t)Nn * sizeof(int));
    int*   unode = (int*)alloc(1024 * sizeof(int));
    int*   cnt   = (int*)alloc(16);
    int*   deg   = (int*)alloc(1024 * sizeof(int));
    int*   off   = (int*)alloc(1025 * sizeof(int));
    int*   fill  = (int*)alloc(1024 * sizeof(int));
    int*   elist = (int*)alloc((size_t)ECAP * sizeof(int));
    float* aval  = (float*)alloc((size_t)ECAP * 8 * sizeof(float));
    float* gemb  = (float*)alloc((size_t)1024 * 512 * sizeof(float));

    hipLaunchKernelGGL(k_init,    dim3(196),  dim3(256),  0, stream, uid, deg, fill, cnt);
    hipLaunchKernelGGL(k_fold,    dim3(1),    dim3(256),  0, stream, gat_fc_w, attn_l, attn_r, wl, wr);
    hipLaunchKernelGGL(k_eler,    dim3(391),  dim3(128),  0, stream, features, wl, wr, el, er);
    hipLaunchKernelGGL(k_mark,    dim3(4),    dim3(256),  0, stream, url, uid, unode, cnt);
    hipLaunchKernelGGL(k_count,   dim3(1563), dim3(256),  0, stream, dst, uid, deg);
    hipLaunchKernelGGL(k_scan,    dim3(1),    dim3(1024), 0, stream, deg, off);
    hipLaunchKernelGGL(k_scatter, dim3(1563), dim3(256),  0, stream, dst, uid, off, fill, elist);
    hipLaunchKernelGGL(k_soft,    dim3(32),   dim3(256),  0, stream, src, elist, off, el, er, unode, cnt, aval);
    hipLaunchKernelGGL(k_gat,     dim3(512),  dim3(256),  0, stream, features, gat_fc_w, gat_res_w, gat_bias,
                       src, cnt, unode, off, elist, aval, gemb);
    hipLaunchKernelGGL(k_mha,     dim3(1024), dim3(256),  0, stream, url, uid, gemb, ln_g, ln_b,
                       wq, wk, wv, fc_w, fc_b, mha_ln_g, mha_ln_b, out_w, out_b,
                       (float*)d_out);
}

// Round 9
// 296.901 us; speedup vs baseline: 4.8416x; 1.1286x over previous
//
#include <hip/hip_runtime.h>
#include <math.h>

#define Nn 50000
#define Ee 400000
#define FSz 256
#define HD_ 512
#define Bb 1024
#define SQS 516   // padded row stride for q/k/ov in LDS

// World model (settled R5/R6): ALL float inputs fp32; OUTPUT fp32.
static __device__ __forceinline__ int clampi(int v, int lo, int hi){
    return v < lo ? lo : (v > hi ? hi : v);
}

// K0: init workspace + (block 196) fold attn into gat_fc_w -> wl,wr [256][8]
__global__ __launch_bounds__(256) void k_init(int* uid, int* fill, int* cnt,
                                              const float* __restrict__ W,
                                              const float* __restrict__ al,
                                              const float* __restrict__ ar,
                                              float* __restrict__ wl, float* __restrict__ wr){
    int t = threadIdx.x;
    if(blockIdx.x == 196){
        __shared__ float sal[512], sar[512];
        sal[t] = al[t]; sal[t+256] = al[t+256];
        sar[t] = ar[t]; sar[t+256] = ar[t+256];
        __syncthreads();
        const float4* Wr = (const float4*)(W + t*512);
        float accl[8] = {0,0,0,0,0,0,0,0};
        float accr[8] = {0,0,0,0,0,0,0,0};
        for(int i = 0; i < 128; i++){
            float4 w = Wr[i];
            int o = 4*i;               // o = h*64 + d
            int h = o >> 6;
            const float* alp = &sal[o];
            const float* arp = &sar[o];
            accl[h] += w.x*alp[0] + w.y*alp[1] + w.z*alp[2] + w.w*alp[3];
            accr[h] += w.x*arp[0] + w.y*arp[1] + w.z*arp[2] + w.w*arp[3];
        }
        #pragma unroll
        for(int h = 0; h < 8; h++){ wl[t*8 + h] = accl[h]; wr[t*8 + h] = accr[h]; }
    } else {
        int i = blockIdx.x * 256 + t;
        if(i < Nn) uid[i] = -1;
        if(i < 1024) fill[i] = 0;
        if(i == 0) cnt[0] = 0;
    }
}

// K2: el,er for all N nodes; float4 feature loads, b128 LDS weight reads.
__global__ __launch_bounds__(128) void k_eler(const float* __restrict__ features,
                                              const float* __restrict__ wl, const float* __restrict__ wr,
                                              float* __restrict__ el, float* __restrict__ er){
    __shared__ float swl[2048], swr[2048];
    int t = threadIdx.x;
    for(int i = t; i < 2048; i += 128){ swl[i] = wl[i]; swr[i] = wr[i]; }
    __syncthreads();
    int n = blockIdx.x * 128 + t;
    if(n >= Nn) return;
    const float4* row = (const float4*)(features + (size_t)n * FSz);
    float4 l0 = {0,0,0,0}, l1 = {0,0,0,0}, r0 = {0,0,0,0}, r1 = {0,0,0,0};
    for(int fp = 0; fp < 64; fp += 2){
        float4 v0 = row[fp], v1 = row[fp + 1];
        float xs[8];
        *(float4*)&xs[0] = v0; *(float4*)&xs[4] = v1;
        int f0 = 4*fp;
        #pragma unroll
        for(int i = 0; i < 8; i++){
            float x = xs[i];
            float4 wa = *(const float4*)&swl[(f0+i)*8];
            float4 wb = *(const float4*)&swl[(f0+i)*8 + 4];
            float4 ra = *(const float4*)&swr[(f0+i)*8];
            float4 rb = *(const float4*)&swr[(f0+i)*8 + 4];
            l0.x += x*wa.x; l0.y += x*wa.y; l0.z += x*wa.z; l0.w += x*wa.w;
            l1.x += x*wb.x; l1.y += x*wb.y; l1.z += x*wb.z; l1.w += x*wb.w;
            r0.x += x*ra.x; r0.y += x*ra.y; r0.z += x*ra.z; r0.w += x*ra.w;
            r1.x += x*rb.x; r1.y += x*rb.y; r1.z += x*rb.z; r1.w += x*rb.w;
        }
    }
    *(float4*)&el[n*8]     = l0;
    *(float4*)&el[n*8 + 4] = l1;
    *(float4*)&er[n*8]     = r0;
    *(float4*)&er[n*8 + 4] = r1;
}

// K3: assign dense ids to unique selected nodes
__global__ __launch_bounds__(256) void k_mark(const int* __restrict__ url, int* uid, int* unode, int* cnt){
    int b = blockIdx.x * 256 + threadIdx.x;
    if(b >= Bb) return;
    int n = clampi(url[b] - 1, 0, Nn - 1);
    int old = atomicCAS(&uid[n], -1, -2);
    if(old == -1){
        int id = atomicAdd(cnt, 1);
        unode[id] = n;
        uid[n] = id;
    }
}

// K6: single edge pass: fixed 64-slot lists; also gathers el rows into dense ew.
__global__ __launch_bounds__(256) void k_scatter(const int* __restrict__ src, const int* __restrict__ dst,
                                                 const int* __restrict__ uid, int* __restrict__ fill,
                                                 int* __restrict__ slist, float* __restrict__ ew,
                                                 const float* __restrict__ el){
    int e = blockIdx.x * 256 + threadIdx.x;
    if(e >= Ee) return;
    int d = dst[e];
    if((unsigned)d >= (unsigned)Nn) return;
    int u = uid[d];
    if(u < 0) return;
    int pos = atomicAdd(&fill[u], 1);
    if(pos >= 64) return;             // P(deg>64 | Poisson(8)) ~ 1e-40
    int s = clampi(src[e], 0, Nn - 1);
    slist[u*64 + pos] = s;
    float4 e0 = *(const float4*)&el[s*8];
    float4 e1 = *(const float4*)&el[s*8 + 4];
    *(float4*)&ew[(size_t)(u*64 + pos)*8]     = e0;
    *(float4*)&ew[(size_t)(u*64 + pos)*8 + 4] = e1;
}

// K7: 2 nodes/block: inline softmax (LDS) -> alpha-combine -> dual GEMV.
__global__ __launch_bounds__(256) void k_gat(const float* __restrict__ features,
                                             const float* __restrict__ Wfc,
                                             const float* __restrict__ Wres,
                                             const float* __restrict__ bias,
                                             const int* __restrict__ cnt, const int* __restrict__ unode,
                                             const int* __restrict__ fill, const int* __restrict__ slist,
                                             const float* __restrict__ ew, const float* __restrict__ er,
                                             float* __restrict__ gemb){
    int t = threadIdx.x;
    int cntv = cnt[0];
    int u0 = blockIdx.x * 2;
    if(u0 >= cntv) return;

    __shared__ float cxs[2][8][256];   // 16 KB
    __shared__ float fres[2][256];     //  2 KB
    __shared__ float sew[2][64][8];    //  4 KB: raw el -> normalized alpha
    __shared__ float ser[2][8];
    __shared__ int   sslist[2][64];

    int deg[2];
    deg[0] = min(fill[u0], 64);
    deg[1] = (u0 + 1 < cntv) ? min(fill[u0 + 1], 64) : 0;

    #pragma unroll
    for(int j = 0; j < 2; j++){
        int u = u0 + j;
        if(t < deg[j]) sslist[j][t] = slist[u*64 + t];
        if(t < deg[j]*8) sew[j][t>>3][t&7] = ew[(size_t)(u*64)*8 + t];
        if(t < 8 && u < cntv) ser[j][t] = er[unode[u]*8 + t];
    }
    __syncthreads();
    // softmax per (node, head): 16 threads, serial over deg (~8)
    if(t < 16){
        int j = t >> 3, h = t & 7;
        int dg = deg[j];
        if(dg > 0){
            float ern = ser[j][h];
            float m = -1e30f;
            for(int i = 0; i < dg; i++){
                float v = sew[j][i][h] + ern;
                v = v > 0.f ? v : 0.2f * v;
                m = fmaxf(m, v);
            }
            float sum = 0.f;
            for(int i = 0; i < dg; i++){
                float v = sew[j][i][h] + ern;
                v = v > 0.f ? v : 0.2f * v;
                float w = expf(v - m);
                sum += w;
                sew[j][i][h] = w;
            }
            float inv = 1.0f / fmaxf(sum, 1e-20f);
            for(int i = 0; i < dg; i++) sew[j][i][h] *= inv;
        }
    }
    __syncthreads();
    // alpha-combine source rows
    #pragma unroll
    for(int j = 0; j < 2; j++){
        int u = u0 + j;
        if(u < cntv) fres[j][t] = features[(size_t)unode[u] * FSz + t];
        else         fres[j][t] = 0.f;
        float cx[8] = {0,0,0,0,0,0,0,0};
        for(int i = 0; i < deg[j]; i++){
            int s = sslist[j][i];
            float x = features[(size_t)s * FSz + t];
            const float* av = &sew[j][i][0];       // wave-uniform broadcast
            #pragma unroll
            for(int h = 0; h < 8; h++) cx[h] += av[h] * x;
        }
        #pragma unroll
        for(int h = 0; h < 8; h++) cxs[j][h][t] = cx[h];
    }
    __syncthreads();

    // dual GEMV: thread owns output cols (2t, 2t+1); h = t>>5 half-wave-uniform
    int h = t >> 5;
    int o0 = 2 * t;
    const float2* Wfc2  = (const float2*)Wfc;
    const float2* Wres2 = (const float2*)Wres;
    float a00 = 0.f, a01 = 0.f, a10 = 0.f, a11 = 0.f;
    for(int f = 0; f < 256; f += 4){
        float2 w0 = Wfc2[(f+0)*256 + t];
        float2 w1 = Wfc2[(f+1)*256 + t];
        float2 w2 = Wfc2[(f+2)*256 + t];
        float2 w3 = Wfc2[(f+3)*256 + t];
        float2 r0 = Wres2[(f+0)*256 + t];
        float2 r1 = Wres2[(f+1)*256 + t];
        float2 r2 = Wres2[(f+2)*256 + t];
        float2 r3 = Wres2[(f+3)*256 + t];
        float4 c0 = *(const float4*)&cxs[0][h][f];
        float4 x0 = *(const float4*)&fres[0][f];
        float4 c1 = *(const float4*)&cxs[1][h][f];
        float4 x1 = *(const float4*)&fres[1][f];
        a00 += c0.x*w0.x + c0.y*w1.x + c0.z*w2.x + c0.w*w3.x + x0.x*r0.x + x0.y*r1.x + x0.z*r2.x + x0.w*r3.x;
        a01 += c0.x*w0.y + c0.y*w1.y + c0.z*w2.y + c0.w*w3.y + x0.x*r0.y + x0.y*r1.y + x0.z*r2.y + x0.w*r3.y;
        a10 += c1.x*w0.x + c1.y*w1.x + c1.z*w2.x + c1.w*w3.x + x1.x*r0.x + x1.y*r1.x + x1.z*r2.x + x1.w*r3.x;
        a11 += c1.x*w0.y + c1.y*w1.y + c1.z*w2.y + c1.w*w3.y + x1.x*r0.y + x1.y*r1.y + x1.z*r2.y + x1.w*r3.y;
    }
    float b0 = bias[o0], b1 = bias[o0 + 1];
    {
        float2* gp = (float2*)(gemb + (size_t)u0 * HD_);
        gp[t] = make_float2(a00 + b0, a01 + b1);
    }
    if(u0 + 1 < cntv){
        float2* gp = (float2*)(gemb + (size_t)(u0 + 1) * HD_);
        gp[t] = make_float2(a10 + b0, a11 + b1);
    }
}

#define QKV_STEP(acc0, acc1, w00, w01, w10, w11) \
    acc0[0]+=xa0.x*w00+xa1.x*w10; acc1[0]+=xa0.x*w01+xa1.x*w11; \
    acc0[1]+=xa0.y*w00+xa1.y*w10; acc1[1]+=xa0.y*w01+xa1.y*w11; \
    acc0[2]+=xa0.z*w00+xa1.z*w10; acc1[2]+=xa0.z*w01+xa1.z*w11; \
    acc0[3]+=xa0.w*w00+xa1.w*w10; acc1[3]+=xa0.w*w01+xa1.w*w11; \
    acc0[4]+=xb0.x*w00+xb1.x*w10; acc1[4]+=xb0.x*w01+xb1.x*w11; \
    acc0[5]+=xb0.y*w00+xb1.y*w10; acc1[5]+=xb0.y*w01+xb1.y*w11; \
    acc0[6]+=xb0.z*w00+xb1.z*w10; acc1[6]+=xb0.z*w01+xb1.z*w11; \
    acc0[7]+=xb0.w*w00+xb1.w*w10; acc1[7]+=xb0.w*w01+xb1.w*w11;

// K8: per batch element. Fused q/k/v projection (x read once from LDS, b128);
// v kept in registers through softmax; all LDS reads b128. 4 blocks/CU.
__global__ __launch_bounds__(256, 4) void k_mha(const int* __restrict__ url, const int* __restrict__ uid,
                                             const float* __restrict__ gemb,
                                             const float* __restrict__ lng, const float* __restrict__ lnb,
                                             const float* __restrict__ wq, const float* __restrict__ wk,
                                             const float* __restrict__ wvp, const float* __restrict__ fcw,
                                             const float* __restrict__ fcb, const float* __restrict__ mlg,
                                             const float* __restrict__ mlb, const float* __restrict__ outw,
                                             const float* __restrict__ outb, float* __restrict__ out){
    __shared__ float A[512];            // xr -> sc (scores) -> yy
    __shared__ float xnT[64*12];        // LN1 out transposed [d][qq], stride 12
    __shared__ float qk[2][8*SQS];      // q,k ; ov overlays q after softmax
    __shared__ float mu8[8], rs8[8], pooled[64];
    float* sc = A;

    int b = blockIdx.x, t = threadIdx.x;
    int n = clampi(url[b] - 1, 0, Nn - 1);
    int u = uid[n];
    if(u < 0) u = 0;
    const float* gp = gemb + (size_t)u * HD_;
    A[t] = gp[t]; A[t + 256] = gp[t + 256];
    __syncthreads();
    if(t < 8){
        float s = 0.f, s2 = 0.f;
        for(int d = 0; d < 64; d++){ float v = A[t*64 + d]; s += v; s2 += v * v; }
        float mu = s * (1.0f/64.0f);
        float var = s2 * (1.0f/64.0f) - mu * mu;
        mu8[t] = mu; rs8[t] = rsqrtf(fmaxf(var, 0.0f) + 1e-6f);
    }
    __syncthreads();
    #pragma unroll
    for(int p = 0; p < 2; p++){
        int i = p*256 + t; int q = i >> 6, d = i & 63;
        xnT[d*12 + q] = (A[i] - mu8[q]) * rs8[q] * lng[d] + lnb[d];
    }
    __syncthreads();
    // ---- fused q,k,v projection: thread owns cols t and t+256 ----
    float aq0[8] = {0,0,0,0,0,0,0,0}, aq1[8] = {0,0,0,0,0,0,0,0};
    float ak0[8] = {0,0,0,0,0,0,0,0}, ak1[8] = {0,0,0,0,0,0,0,0};
    float av0[8] = {0,0,0,0,0,0,0,0}, av1[8] = {0,0,0,0,0,0,0,0};
    for(int d = 0; d < 64; d += 2){
        float q00 = wq[d*512 + t],       q01 = wq[d*512 + t + 256];
        float q10 = wq[(d+1)*512 + t],   q11 = wq[(d+1)*512 + t + 256];
        float k00 = wk[d*512 + t],       k01 = wk[d*512 + t + 256];
        float k10 = wk[(d+1)*512 + t],   k11 = wk[(d+1)*512 + t + 256];
        float v00 = wvp[d*512 + t],      v01 = wvp[d*512 + t + 256];
        float v10 = wvp[(d+1)*512 + t],  v11 = wvp[(d+1)*512 + t + 256];
        float4 xa0 = *(const float4*)&xnT[d*12];
        float4 xb0 = *(const float4*)&xnT[d*12 + 4];
        float4 xa1 = *(const float4*)&xnT[(d+1)*12];
        float4 xb1 = *(const float4*)&xnT[(d+1)*12 + 4];
        QKV_STEP(aq0, aq1, q00, q01, q10, q11)
        QKV_STEP(ak0, ak1, k00, k01, k10, k11)
        QKV_STEP(av0, av1, v00, v01, v10, v11)
    }
    #pragma unroll
    for(int qq = 0; qq < 8; qq++){
        qk[0][qq*SQS + t]       = aq0[qq];
        qk[0][qq*SQS + t + 256] = aq1[qq];
        qk[1][qq*SQS + t]       = ak0[qq];
        qk[1][qq*SQS + t + 256] = ak1[qq];
    }
    __syncthreads();
    // ---- scores sc[nh*64 + qq*8 + kk], b128 reads ----
    #pragma unroll
    for(int p = 0; p < 2; p++){
        int idx = p*256 + t;
        int nh = idx >> 6, qq = (idx >> 3) & 7, kk = idx & 7;
        const float* qrow = &qk[0][qq*SQS + nh*64];
        const float* krow = &qk[1][kk*SQS + nh*64];
        float s = 0.f;
        for(int d = 0; d < 64; d += 4){
            float4 qv = *(const float4*)&qrow[d];
            float4 kv = *(const float4*)&krow[d];
            s += qv.x*kv.x + qv.y*kv.y + qv.z*kv.z + qv.w*kv.w;
        }
        sc[idx] = s * 0.125f;
    }
    __syncthreads();
    if(t < 64){
        float mx = -1e30f;
        #pragma unroll
        for(int k = 0; k < 8; k++) mx = fmaxf(mx, sc[t*8 + k]);
        float e[8]; float s = 0.f;
        #pragma unroll
        for(int k = 0; k < 8; k++){ e[k] = expf(sc[t*8 + k] - mx); s += e[k]; }
        float inv = 1.0f / s;
        #pragma unroll
        for(int k = 0; k < 8; k++) sc[t*8 + k] = e[k] * inv;
    }
    __syncthreads();
    // ---- attn @ v from registers -> ov overlays q (qk[0]) ----
    {
        int nh0 = t >> 6;                    // col t -> nh0; col t+256 -> nh0+4
        #pragma unroll
        for(int qq = 0; qq < 8; qq++){
            float4 s0a = *(const float4*)&sc[nh0*64 + qq*8];
            float4 s0b = *(const float4*)&sc[nh0*64 + qq*8 + 4];
            float4 s1a = *(const float4*)&sc[(nh0+4)*64 + qq*8];
            float4 s1b = *(const float4*)&sc[(nh0+4)*64 + qq*8 + 4];
            float o0 = s0a.x*av0[0] + s0a.y*av0[1] + s0a.z*av0[2] + s0a.w*av0[3]
                     + s0b.x*av0[4] + s0b.y*av0[5] + s0b.z*av0[6] + s0b.w*av0[7];
            float o1 = s1a.x*av1[0] + s1a.y*av1[1] + s1a.z*av1[2] + s1a.w*av1[3]
                     + s1b.x*av1[4] + s1b.y*av1[5] + s1b.z*av1[6] + s1b.w*av1[7];
            qk[0][qq*SQS + t]       = o0;
            qk[0][qq*SQS + t + 256] = o1;
        }
    }
    __syncthreads();
    // ---- fc + bias + residual -> A (sc dead after attn phase) ----
    {
        int g = t & 31, qq = t >> 5;
        int dd0 = 2 * g;
        const float* orow = &qk[0][qq*SQS];
        const float2* fw2 = (const float2*)fcw;       // [512][32] float2
        float a0 = 0.f, a1 = 0.f;
        for(int k = 0; k < 512; k += 8){
            float2 f0 = fw2[(k+0)*32 + g];
            float2 f1 = fw2[(k+1)*32 + g];
            float2 f2 = fw2[(k+2)*32 + g];
            float2 f3 = fw2[(k+3)*32 + g];
            float2 f4 = fw2[(k+4)*32 + g];
            float2 f5 = fw2[(k+5)*32 + g];
            float2 f6 = fw2[(k+6)*32 + g];
            float2 f7 = fw2[(k+7)*32 + g];
            float4 x0 = *(const float4*)&orow[k];
            float4 x1 = *(const float4*)&orow[k + 4];
            a0 += x0.x*f0.x + x0.y*f1.x + x0.z*f2.x + x0.w*f3.x
                + x1.x*f4.x + x1.y*f5.x + x1.z*f6.x + x1.w*f7.x;
            a1 += x0.x*f0.y + x0.y*f1.y + x0.z*f2.y + x0.w*f3.y
                + x1.x*f4.y + x1.y*f5.y + x1.z*f6.y + x1.w*f7.y;
        }
        A[qq*64 + dd0]     = a0 + fcb[dd0]     + xnT[(dd0)*12 + qq];
        A[qq*64 + dd0 + 1] = a1 + fcb[dd0 + 1] + xnT[(dd0+1)*12 + qq];
    }
    __syncthreads();
    if(t < 8){
        float s = 0.f, s2 = 0.f;
        for(int d = 0; d < 64; d++){ float v = A[t*64 + d]; s += v; s2 += v * v; }
        float mu = s * (1.0f/64.0f);
        float var = s2 * (1.0f/64.0f) - mu * mu;
        mu8[t] = mu; rs8[t] = rsqrtf(fmaxf(var, 0.0f) + 1e-6f);
    }
    __syncthreads();
    if(t < 64){
        float g2 = mlg[t], bb = mlb[t];
        float s = 0.f;
        #pragma unroll
        for(int qq = 0; qq < 8; qq++)
            s += (A[qq*64 + t] - mu8[qq]) * rs8[qq] * g2 + bb;
        pooled[t] = s;
    }
    __syncthreads();
    if(t < 2){
        float s = outb[t];
        for(int d = 0; d < 64; d++) s += pooled[d] * outw[d*2 + t];
        out[b*2 + t] = s;
    }
}

extern "C" void kernel_launch(void* const* d_in, const int* in_sizes, int n_in,
                              void* d_out, int out_size, void* d_ws, size_t ws_size,
                              hipStream_t stream){
    (void)in_sizes; (void)n_in; (void)out_size; (void)ws_size;
    const float* features  = (const float*)d_in[0];
    const int*   src       = (const int*)d_in[1];
    const int*   dst       = (const int*)d_in[2];
    const int*   url       = (const int*)d_in[3];
    const float* gat_fc_w  = (const float*)d_in[4];
    const float* attn_l    = (const float*)d_in[5];
    const float* attn_r    = (const float*)d_in[6];
    const float* gat_res_w = (const float*)d_in[7];
    const float* gat_bias  = (const float*)d_in[8];
    const float* ln_g      = (const float*)d_in[9];
    const float* ln_b      = (const float*)d_in[10];
    const float* wq        = (const float*)d_in[11];
    const float* wk        = (const float*)d_in[12];
    const float* wv        = (const float*)d_in[13];
    const float* fc_w      = (const float*)d_in[14];
    const float* fc_b      = (const float*)d_in[15];
    const float* mha_ln_g  = (const float*)d_in[16];
    const float* mha_ln_b  = (const float*)d_in[17];
    const float* out_w     = (const float*)d_in[18];
    const float* out_b     = (const float*)d_in[19];

    char* base = (char*)d_ws;
    size_t cur = 0;
    auto alloc = [&](size_t nbytes) -> void* {
        void* p = base + cur;
        cur = (cur + nbytes + 255) & ~(size_t)255;
        return p;
    };
    float* wl    = (float*)alloc(2048 * sizeof(float));
    float* wr    = (float*)alloc(2048 * sizeof(float));
    float* el    = (float*)alloc((size_t)Nn * 8 * sizeof(float));
    float* er    = (float*)alloc((size_t)Nn * 8 * sizeof(float));
    int*   uid   = (int*)alloc((size_t)Nn * sizeof(int));
    int*   unode = (int*)alloc(1024 * sizeof(int));
    int*   cnt   = (int*)alloc(16);
    int*   fill  = (int*)alloc(1024 * sizeof(int));
    int*   slist = (int*)alloc((size_t)1024 * 64 * sizeof(int));
    float* ew    = (float*)alloc((size_t)1024 * 64 * 8 * sizeof(float));
    float* gemb  = (float*)alloc((size_t)1024 * 512 * sizeof(float));
    // total ws ~8.3 MB

    hipLaunchKernelGGL(k_init,    dim3(197),  dim3(256), 0, stream, uid, fill, cnt,
                       gat_fc_w, attn_l, attn_r, wl, wr);
    hipLaunchKernelGGL(k_eler,    dim3(391),  dim3(128), 0, stream, features, wl, wr, el, er);
    hipLaunchKernelGGL(k_mark,    dim3(4),    dim3(256), 0, stream, url, uid, unode, cnt);
    hipLaunchKernelGGL(k_scatter, dim3(1563), dim3(256), 0, stream, src, dst, uid, fill, slist, ew, el);
    hipLaunchKernelGGL(k_gat,     dim3(512),  dim3(256), 0, stream, features, gat_fc_w, gat_res_w, gat_bias,
                       cnt, unode, fill, slist, ew, er, gemb);
    hipLaunchKernelGGL(k_mha,     dim3(1024), dim3(256), 0, stream, url, uid, gemb, ln_g, ln_b,
                       wq, wk, wv, fc_w, fc_b, mha_ln_g, mha_ln_b, out_w, out_b,
                       (float*)d_out);
}

// Round 10
// 242.766 us; speedup vs baseline: 5.9212x; 1.2230x over previous
//
#include <hip/hip_runtime.h>
#include <math.h>

#define Nn 50000
#define Ee 400000
#define FSz 256
#define HD_ 512
#define Bb 1024

// World model (settled R5/R6): ALL float inputs fp32; OUTPUT fp32.
static __device__ __forceinline__ int clampi(int v, int lo, int hi){
    return v < lo ? lo : (v > hi ? hi : v);
}
static __device__ __forceinline__ unsigned short f2bf(float f){
    unsigned int u = __float_as_uint(f);
    unsigned int r = u + 0x7FFFu + ((u >> 16) & 1u);
    return (unsigned short)(r >> 16);
}
static __device__ __forceinline__ float bflo(unsigned int v){ return __uint_as_float(v << 16); }
static __device__ __forceinline__ float bfhi(unsigned int v){ return __uint_as_float(v & 0xFFFF0000u); }

// K0: init workspace + (block 196) fold attn into gat_fc_w -> wl,wr TRANSPOSED [8][256]
__global__ __launch_bounds__(256) void k_init(int* uid, int* fill, int* cnt,
                                              const float* __restrict__ W,
                                              const float* __restrict__ al,
                                              const float* __restrict__ ar,
                                              float* __restrict__ wl, float* __restrict__ wr){
    int t = threadIdx.x;
    if(blockIdx.x == 196){
        __shared__ float sal[512], sar[512];
        sal[t] = al[t]; sal[t+256] = al[t+256];
        sar[t] = ar[t]; sar[t+256] = ar[t+256];
        __syncthreads();
        const float4* Wr = (const float4*)(W + t*512);
        float accl[8] = {0,0,0,0,0,0,0,0};
        float accr[8] = {0,0,0,0,0,0,0,0};
        for(int i = 0; i < 128; i++){
            float4 w = Wr[i];
            int o = 4*i;               // o = h*64 + d
            int h = o >> 6;
            const float* alp = &sal[o];
            const float* arp = &sar[o];
            accl[h] += w.x*alp[0] + w.y*alp[1] + w.z*alp[2] + w.w*alp[3];
            accr[h] += w.x*arp[0] + w.y*arp[1] + w.z*arp[2] + w.w*arp[3];
        }
        #pragma unroll
        for(int h = 0; h < 8; h++){ wl[h*256 + t] = accl[h]; wr[h*256 + t] = accr[h]; }
    } else {
        int i = blockIdx.x * 256 + t;
        if(i < Nn) uid[i] = -1;
        if(i < 1024) fill[i] = 0;
        if(i == 0) cnt[0] = 0;
    }
}

// K1: assign dense ids to unique selected nodes
__global__ __launch_bounds__(256) void k_mark(const int* __restrict__ url, int* uid, int* unode, int* cnt){
    int b = blockIdx.x * 256 + threadIdx.x;
    if(b >= Bb) return;
    int n = clampi(url[b] - 1, 0, Nn - 1);
    int old = atomicCAS(&uid[n], -1, -2);
    if(old == -1){
        int id = atomicAdd(cnt, 1);
        unode[id] = n;
        uid[n] = id;
    }
}

// K2: single edge pass: fixed 64-slot source lists per selected node
__global__ __launch_bounds__(256) void k_scatter(const int* __restrict__ src, const int* __restrict__ dst,
                                                 const int* __restrict__ uid, int* __restrict__ fill,
                                                 int* __restrict__ slist){
    int e = blockIdx.x * 256 + threadIdx.x;
    if(e >= Ee) return;
    int d = dst[e];
    if((unsigned)d >= (unsigned)Nn) return;
    int u = uid[d];
    if(u < 0) return;
    int pos = atomicAdd(&fill[u], 1);
    if(pos >= 64) return;             // P(deg>64 | Poisson(8)) ~ 1e-40
    slist[u*64 + pos] = clampi(src[e], 0, Nn - 1);
}

// K3: 2 nodes/block: per-edge el via wave-reduce, er likewise, softmax,
// alpha-combine, dual GEMV. (k_eler is gone — el computed only where used.)
__global__ __launch_bounds__(256) void k_gat(const float* __restrict__ features,
                                             const float* __restrict__ Wfc,
                                             const float* __restrict__ Wres,
                                             const float* __restrict__ bias,
                                             const float* __restrict__ wl,   // [8][256] transposed
                                             const float* __restrict__ wr,
                                             const int* __restrict__ cnt, const int* __restrict__ unode,
                                             const int* __restrict__ fill, const int* __restrict__ slist,
                                             float* __restrict__ gemb){
    int t = threadIdx.x;
    int lane = t & 63, wv = t >> 6;
    int cntv = cnt[0];
    int u0 = blockIdx.x * 2;
    if(u0 >= cntv) return;

    __shared__ float swl[2048], swr[2048];   // transposed [h][256]
    __shared__ float cxs[2][8][256];
    __shared__ float fres[2][256];
    __shared__ float sew[2][64][8];          // el per edge -> normalized alpha
    __shared__ float ser[2][8];
    __shared__ int   sslist[2][64];

    for(int i = t; i < 2048; i += 256){ swl[i] = wl[i]; swr[i] = wr[i]; }

    int dg[2];
    dg[0] = min(fill[u0], 64);
    dg[1] = (u0 + 1 < cntv) ? min(fill[u0 + 1], 64) : 0;
    #pragma unroll
    for(int j = 0; j < 2; j++){
        int u = u0 + j;
        if(t < dg[j]) sslist[j][t] = slist[u*64 + t];
        if(u < cntv) fres[j][t] = features[(size_t)unode[u] * FSz + t];
        else         fres[j][t] = 0.f;
    }
    __syncthreads();

    // ---- pass A: per-task wave-level dot products. tasks = edges (el) + 2 er rows
    int total = dg[0] + dg[1];
    for(int tau = wv; tau < total + 2; tau += 4){
        int j, i, s, isEr;
        if(tau < dg[0]){ j = 0; i = tau; s = sslist[0][i]; isEr = 0; }
        else if(tau < total){ j = 1; i = tau - dg[0]; s = sslist[1][i]; isEr = 0; }
        else { j = tau - total; i = 0; s = (u0 + j < cntv) ? unode[u0 + j] : 0; isEr = 1; }
        float4 x = *(const float4*)(features + (size_t)s * FSz + 4*lane);
        const float* Wt = isEr ? swr : swl;
        float p[8];
        #pragma unroll
        for(int h = 0; h < 8; h++){
            float4 w = *(const float4*)&Wt[h*256 + 4*lane];   // conflict-free b128
            p[h] = x.x*w.x + x.y*w.y + x.z*w.z + x.w*w.w;
        }
        #pragma unroll
        for(int h = 0; h < 8; h++){
            #pragma unroll
            for(int m = 32; m >= 1; m >>= 1) p[h] += __shfl_xor(p[h], m, 64);
        }
        if(lane == 0){
            if(isEr){
                #pragma unroll
                for(int h = 0; h < 8; h++) ser[j][h] = p[h];
            } else {
                #pragma unroll
                for(int h = 0; h < 8; h++) sew[j][i][h] = p[h];
            }
        }
    }
    __syncthreads();
    // ---- softmax per (node, head): 16 threads, serial over deg (~8)
    if(t < 16){
        int j = t >> 3, h = t & 7;
        int dgj = dg[j];
        if(dgj > 0){
            float ern = ser[j][h];
            float m = -1e30f;
            for(int i = 0; i < dgj; i++){
                float v = sew[j][i][h] + ern;
                v = v > 0.f ? v : 0.2f * v;
                m = fmaxf(m, v);
            }
            float sum = 0.f;
            for(int i = 0; i < dgj; i++){
                float v = sew[j][i][h] + ern;
                v = v > 0.f ? v : 0.2f * v;
                float w = expf(v - m);
                sum += w;
                sew[j][i][h] = w;
            }
            float inv = 1.0f / fmaxf(sum, 1e-20f);
            for(int i = 0; i < dgj; i++) sew[j][i][h] *= inv;
        }
    }
    __syncthreads();
    // ---- pass B: alpha-combine source rows
    #pragma unroll
    for(int j = 0; j < 2; j++){
        float cx[8] = {0,0,0,0,0,0,0,0};
        for(int i = 0; i < dg[j]; i++){
            int s = sslist[j][i];
            float x = features[(size_t)s * FSz + t];
            const float* av = &sew[j][i][0];       // wave-uniform broadcast
            #pragma unroll
            for(int h = 0; h < 8; h++) cx[h] += av[h] * x;
        }
        #pragma unroll
        for(int h = 0; h < 8; h++) cxs[j][h][t] = cx[h];
    }
    __syncthreads();

    // ---- dual GEMV: thread owns output cols (2t, 2t+1); h = t>>5 half-wave-uniform
    int h = t >> 5;
    int o0 = 2 * t;
    const float2* Wfc2  = (const float2*)Wfc;
    const float2* Wres2 = (const float2*)Wres;
    float a00 = 0.f, a01 = 0.f, a10 = 0.f, a11 = 0.f;
    for(int f = 0; f < 256; f += 4){
        float2 w0 = Wfc2[(f+0)*256 + t];
        float2 w1 = Wfc2[(f+1)*256 + t];
        float2 w2 = Wfc2[(f+2)*256 + t];
        float2 w3 = Wfc2[(f+3)*256 + t];
        float2 r0 = Wres2[(f+0)*256 + t];
        float2 r1 = Wres2[(f+1)*256 + t];
        float2 r2 = Wres2[(f+2)*256 + t];
        float2 r3 = Wres2[(f+3)*256 + t];
        float4 c0 = *(const float4*)&cxs[0][h][f];
        float4 x0 = *(const float4*)&fres[0][f];
        float4 c1 = *(const float4*)&cxs[1][h][f];
        float4 x1 = *(const float4*)&fres[1][f];
        a00 += c0.x*w0.x + c0.y*w1.x + c0.z*w2.x + c0.w*w3.x + x0.x*r0.x + x0.y*r1.x + x0.z*r2.x + x0.w*r3.x;
        a01 += c0.x*w0.y + c0.y*w1.y + c0.z*w2.y + c0.w*w3.y + x0.x*r0.y + x0.y*r1.y + x0.z*r2.y + x0.w*r3.y;
        a10 += c1.x*w0.x + c1.y*w1.x + c1.z*w2.x + c1.w*w3.x + x1.x*r0.x + x1.y*r1.x + x1.z*r2.x + x1.w*r3.x;
        a11 += c1.x*w0.y + c1.y*w1.y + c1.z*w2.y + c1.w*w3.y + x1.x*r0.y + x1.y*r1.y + x1.z*r2.y + x1.w*r3.y;
    }
    float b0 = bias[o0], b1 = bias[o0 + 1];
    {
        float2* gp = (float2*)(gemb + (size_t)u0 * HD_);
        gp[t] = make_float2(a00 + b0, a01 + b1);
    }
    if(u0 + 1 < cntv){
        float2* gp = (float2*)(gemb + (size_t)(u0 + 1) * HD_);
        gp[t] = make_float2(a10 + b0, a11 + b1);
    }
}

// K4: per batch element. bf16 LDS (xn/q/k/ov), fp32 accum + fp32 residual.
// fc wave-split kills inter-wave fcw redundancy. LDS ~22 KB -> 6 blocks/CU.
__global__ __launch_bounds__(256, 6) void k_mha(const int* __restrict__ url, const int* __restrict__ uid,
                                             const float* __restrict__ gemb,
                                             const float* __restrict__ lng, const float* __restrict__ lnb,
                                             const float* __restrict__ wq, const float* __restrict__ wk,
                                             const float* __restrict__ wvp, const float* __restrict__ fcw,
                                             const float* __restrict__ fcb, const float* __restrict__ mlg,
                                             const float* __restrict__ mlb, const float* __restrict__ outw,
                                             const float* __restrict__ outb, float* __restrict__ out){
    __shared__ float A[512];                 // xr -> sc -> yy
    __shared__ float xnF[512];               // fp32 LN1 out (residual), [qq*64+dd]
    __shared__ unsigned short xnT[64*8];     // bf16 LN1 out, [d][qq]
    __shared__ unsigned short qkb[2*8*520];  // bf16 q | k ; later: ov (first half) + fp32 partials (second half)
    __shared__ float mu8[8], rs8[8], pooled[64];

    int b = blockIdx.x, t = threadIdx.x;
    int lane = t & 63, wv = t >> 6;
    int n = clampi(url[b] - 1, 0, Nn - 1);
    int u = uid[n];
    if(u < 0) u = 0;
    const float* gp = gemb + (size_t)u * HD_;
    A[t] = gp[t]; A[t + 256] = gp[t + 256];
    __syncthreads();
    if(t < 8){
        float s = 0.f, s2 = 0.f;
        for(int d = 0; d < 64; d++){ float v = A[t*64 + d]; s += v; s2 += v * v; }
        float mu = s * (1.0f/64.0f);
        float var = s2 * (1.0f/64.0f) - mu * mu;
        mu8[t] = mu; rs8[t] = rsqrtf(fmaxf(var, 0.0f) + 1e-6f);
    }
    __syncthreads();
    #pragma unroll
    for(int p = 0; p < 2; p++){
        int i = p*256 + t; int q = i >> 6, d = i & 63;
        float xv = (A[i] - mu8[q]) * rs8[q] * lng[d] + lnb[d];
        xnF[i] = xv;
        xnT[d*8 + q] = f2bf(xv);
    }
    __syncthreads();
    // ---- q,k projection: thread owns cols t and t+256; 1 b128 xn read per d ----
    float aq0[8] = {0,0,0,0,0,0,0,0}, aq1[8] = {0,0,0,0,0,0,0,0};
    float ak0[8] = {0,0,0,0,0,0,0,0}, ak1[8] = {0,0,0,0,0,0,0,0};
    #pragma unroll 4
    for(int d = 0; d < 64; d++){
        float q0 = wq[d*512 + t], q1 = wq[d*512 + t + 256];
        float k0 = wk[d*512 + t], k1 = wk[d*512 + t + 256];
        uint4 xp = *(const uint4*)&xnT[d*8];
        float xv[8] = { bflo(xp.x), bfhi(xp.x), bflo(xp.y), bfhi(xp.y),
                        bflo(xp.z), bfhi(xp.z), bflo(xp.w), bfhi(xp.w) };
        #pragma unroll
        for(int r = 0; r < 8; r++){
            aq0[r] += xv[r]*q0; aq1[r] += xv[r]*q1;
            ak0[r] += xv[r]*k0; ak1[r] += xv[r]*k1;
        }
    }
    #pragma unroll
    for(int qq = 0; qq < 8; qq++){
        qkb[qq*520 + t]              = f2bf(aq0[qq]);
        qkb[qq*520 + t + 256]        = f2bf(aq1[qq]);
        qkb[4160 + qq*520 + t]       = f2bf(ak0[qq]);
        qkb[4160 + qq*520 + t + 256] = f2bf(ak1[qq]);
    }
    __syncthreads();
    // ---- scores sc[nh*64 + qq*8 + kk] from bf16 q,k ----
    #pragma unroll
    for(int p = 0; p < 2; p++){
        int idx = p*256 + t;
        int nh = idx >> 6, qq = (idx >> 3) & 7, kk = idx & 7;
        const unsigned short* qrow = &qkb[qq*520 + nh*64];
        const unsigned short* krow = &qkb[4160 + kk*520 + nh*64];
        float s = 0.f;
        #pragma unroll
        for(int d8 = 0; d8 < 64; d8 += 8){
            uint4 qv = *(const uint4*)&qrow[d8];
            uint4 kv = *(const uint4*)&krow[d8];
            s += bflo(qv.x)*bflo(kv.x) + bfhi(qv.x)*bfhi(kv.x)
               + bflo(qv.y)*bflo(kv.y) + bfhi(qv.y)*bfhi(kv.y)
               + bflo(qv.z)*bflo(kv.z) + bfhi(qv.z)*bfhi(kv.z)
               + bflo(qv.w)*bflo(kv.w) + bfhi(qv.w)*bfhi(kv.w);
        }
        A[idx] = s * 0.125f;
    }
    __syncthreads();
    if(t < 64){
        float mx = -1e30f;
        #pragma unroll
        for(int k = 0; k < 8; k++) mx = fmaxf(mx, A[t*8 + k]);
        float e[8]; float s = 0.f;
        #pragma unroll
        for(int k = 0; k < 8; k++){ e[k] = expf(A[t*8 + k] - mx); s += e[k]; }
        float inv = 1.0f / s;
        #pragma unroll
        for(int k = 0; k < 8; k++) A[t*8 + k] = e[k] * inv;
    }
    __syncthreads();
    // ---- v projection (regs only) ----
    float av0[8] = {0,0,0,0,0,0,0,0}, av1[8] = {0,0,0,0,0,0,0,0};
    #pragma unroll 4
    for(int d = 0; d < 64; d++){
        float v0 = wvp[d*512 + t], v1 = wvp[d*512 + t + 256];
        uint4 xp = *(const uint4*)&xnT[d*8];
        float xv[8] = { bflo(xp.x), bfhi(xp.x), bflo(xp.y), bfhi(xp.y),
                        bflo(xp.z), bfhi(xp.z), bflo(xp.w), bfhi(xp.w) };
        #pragma unroll
        for(int r = 0; r < 8; r++){ av0[r] += xv[r]*v0; av1[r] += xv[r]*v1; }
    }
    // ---- attn @ v -> ov (bf16) into q region (q,k dead after scores) ----
    {
        int nh0 = wv;                        // col t -> nh0 ; col t+256 -> nh0+4
        #pragma unroll
        for(int qq = 0; qq < 8; qq++){
            const float* s0 = &A[nh0*64 + qq*8];
            const float* s1 = &A[(nh0+4)*64 + qq*8];
            float4 a0 = *(const float4*)s0, b0 = *(const float4*)(s0 + 4);
            float4 a1 = *(const float4*)s1, b1 = *(const float4*)(s1 + 4);
            float o0 = a0.x*av0[0] + a0.y*av0[1] + a0.z*av0[2] + a0.w*av0[3]
                     + b0.x*av0[4] + b0.y*av0[5] + b0.z*av0[6] + b0.w*av0[7];
            float o1 = a1.x*av1[0] + a1.y*av1[1] + a1.z*av1[2] + a1.w*av1[3]
                     + b1.x*av1[4] + b1.y*av1[5] + b1.z*av1[6] + b1.w*av1[7];
            qkb[qq*520 + t]       = f2bf(o0);
            qkb[qq*520 + t + 256] = f2bf(o1);
        }
    }
    __syncthreads();
    // ---- fc wave-split: wave wv owns k in [wv*128, wv*128+128) for ALL 512 outputs ----
    {
        float* P = (float*)&qkb[4160];       // 8 KB partials [4][512] (k region dead)
        int g = lane & 31;
        int qh = lane >> 5;                   // 0 or 1
        int k0 = wv * 128;
        float a[4][2] = {{0,0},{0,0},{0,0},{0,0}};
        const float2* fw2 = (const float2*)fcw;   // [512][32] float2
        for(int k = k0; k < k0 + 128; k += 8){
            float2 f0 = fw2[(k+0)*32 + g];
            float2 f1 = fw2[(k+1)*32 + g];
            float2 f2 = fw2[(k+2)*32 + g];
            float2 f3 = fw2[(k+3)*32 + g];
            float2 f4 = fw2[(k+4)*32 + g];
            float2 f5 = fw2[(k+5)*32 + g];
            float2 f6 = fw2[(k+6)*32 + g];
            float2 f7 = fw2[(k+7)*32 + g];
            #pragma unroll
            for(int jq = 0; jq < 4; jq++){
                int qq = qh*4 + jq;
                uint4 op = *(const uint4*)&qkb[qq*520 + k];   // 8 bf16 ov values
                float x0 = bflo(op.x), x1 = bfhi(op.x), x2 = bflo(op.y), x3 = bfhi(op.y);
                float x4 = bflo(op.z), x5 = bfhi(op.z), x6 = bflo(op.w), x7 = bfhi(op.w);
                a[jq][0] += x0*f0.x + x1*f1.x + x2*f2.x + x3*f3.x + x4*f4.x + x5*f5.x + x6*f6.x + x7*f7.x;
                a[jq][1] += x0*f0.y + x1*f1.y + x2*f2.y + x3*f3.y + x4*f4.y + x5*f5.y + x6*f6.y + x7*f7.y;
            }
        }
        __syncthreads();   // k region fully consumed by scores long ago; ensure all ov reads done before P overwrite? P==k region; ov reads are this loop's own. Barrier orders P writes after all waves' ov reads of qkb head (disjoint) — main purpose: partials visible below.
        #pragma unroll
        for(int jq = 0; jq < 4; jq++){
            int qq = qh*4 + jq;
            *(float2*)&P[wv*512 + qq*64 + 2*g] = make_float2(a[jq][0], a[jq][1]);
        }
        __syncthreads();
        // combine partials + bias + fp32 residual -> yy in A (sc dead after attn)
        #pragma unroll
        for(int p = 0; p < 2; p++){
            int o = p*256 + t;
            int dd = o & 63;
            A[o] = P[o] + P[512 + o] + P[1024 + o] + P[1536 + o] + fcb[dd] + xnF[o];
        }
    }
    __syncthreads();
    if(t < 8){
        float s = 0.f, s2 = 0.f;
        for(int d = 0; d < 64; d++){ float v = A[t*64 + d]; s += v; s2 += v * v; }
        float mu = s * (1.0f/64.0f);
        float var = s2 * (1.0f/64.0f) - mu * mu;
        mu8[t] = mu; rs8[t] = rsqrtf(fmaxf(var, 0.0f) + 1e-6f);
    }
    __syncthreads();
    if(t < 64){
        float g2 = mlg[t], bb = mlb[t];
        float s = 0.f;
        #pragma unroll
        for(int qq = 0; qq < 8; qq++)
            s += (A[qq*64 + t] - mu8[qq]) * rs8[qq] * g2 + bb;
        pooled[t] = s;
    }
    __syncthreads();
    if(t < 2){
        float s = outb[t];
        for(int d = 0; d < 64; d++) s += pooled[d] * outw[d*2 + t];
        out[b*2 + t] = s;
    }
}

extern "C" void kernel_launch(void* const* d_in, const int* in_sizes, int n_in,
                              void* d_out, int out_size, void* d_ws, size_t ws_size,
                              hipStream_t stream){
    (void)in_sizes; (void)n_in; (void)out_size; (void)ws_size;
    const float* features  = (const float*)d_in[0];
    const int*   src       = (const int*)d_in[1];
    const int*   dst       = (const int*)d_in[2];
    const int*   url       = (const int*)d_in[3];
    const float* gat_fc_w  = (const float*)d_in[4];
    const float* attn_l    = (const float*)d_in[5];
    const float* attn_r    = (const float*)d_in[6];
    const float* gat_res_w = (const float*)d_in[7];
    const float* gat_bias  = (const float*)d_in[8];
    const float* ln_g      = (const float*)d_in[9];
    const float* ln_b      = (const float*)d_in[10];
    const float* wq        = (const float*)d_in[11];
    const float* wk        = (const float*)d_in[12];
    const float* wv        = (const float*)d_in[13];
    const float* fc_w      = (const float*)d_in[14];
    const float* fc_b      = (const float*)d_in[15];
    const float* mha_ln_g  = (const float*)d_in[16];
    const float* mha_ln_b  = (const float*)d_in[17];
    const float* out_w     = (const float*)d_in[18];
    const float* out_b     = (const float*)d_in[19];

    char* base = (char*)d_ws;
    size_t cur = 0;
    auto alloc = [&](size_t nbytes) -> void* {
        void* p = base + cur;
        cur = (cur + nbytes + 255) & ~(size_t)255;
        return p;
    };
    float* wl    = (float*)alloc(2048 * sizeof(float));   // transposed [8][256]
    float* wr    = (float*)alloc(2048 * sizeof(float));
    int*   uid   = (int*)alloc((size_t)Nn * sizeof(int));
    int*   unode = (int*)alloc(1024 * sizeof(int));
    int*   cnt   = (int*)alloc(16);
    int*   fill  = (int*)alloc(1024 * sizeof(int));
    int*   slist = (int*)alloc((size_t)1024 * 64 * sizeof(int));
    float* gemb  = (float*)alloc((size_t)1024 * 512 * sizeof(float));

    hipLaunchKernelGGL(k_init,    dim3(197),  dim3(256), 0, stream, uid, fill, cnt,
                       gat_fc_w, attn_l, attn_r, wl, wr);
    hipLaunchKernelGGL(k_mark,    dim3(4),    dim3(256), 0, stream, url, uid, unode, cnt);
    hipLaunchKernelGGL(k_scatter, dim3(1563), dim3(256), 0, stream, src, dst, uid, fill, slist);
    hipLaunchKernelGGL(k_gat,     dim3(512),  dim3(256), 0, stream, features, gat_fc_w, gat_res_w, gat_bias,
                       wl, wr, cnt, unode, fill, slist, gemb);
    hipLaunchKernelGGL(k_mha,     dim3(1024), dim3(256), 0, stream, url, uid, gemb, ln_g, ln_b,
                       wq, wk, wv, fc_w, fc_b, mha_ln_g, mha_ln_b, out_w, out_b,
                       (float*)d_out);
}

// Round 11
// 238.204 us; speedup vs baseline: 6.0346x; 1.0192x over previous
//
#include <hip/hip_runtime.h>
#include <math.h>

#define Nn 50000
#define Ee 400000
#define FSz 256
#define HD_ 512
#define Bb 1024

// World model (settled R5/R6): ALL float inputs fp32; OUTPUT fp32.
static __device__ __forceinline__ int clampi(int v, int lo, int hi){
    return v < lo ? lo : (v > hi ? hi : v);
}
static __device__ __forceinline__ unsigned short f2bf(float f){
    unsigned int u = __float_as_uint(f);
    unsigned int r = u + 0x7FFFu + ((u >> 16) & 1u);
    return (unsigned short)(r >> 16);
}
static __device__ __forceinline__ float bflo(unsigned int v){ return __uint_as_float(v << 16); }
static __device__ __forceinline__ float bfhi(unsigned int v){ return __uint_as_float(v & 0xFFFF0000u); }

// K1: blocks 0-3: assign dense ids to unique selected nodes.
//     block 4: fold attn_l/attn_r into gat_fc_w -> wl,wr TRANSPOSED [8][256].
__global__ __launch_bounds__(256) void k_mark(const int* __restrict__ url, int* uid, int* unode, int* cnt,
                                              const float* __restrict__ W,
                                              const float* __restrict__ al,
                                              const float* __restrict__ ar,
                                              float* __restrict__ wl, float* __restrict__ wr){
    int t = threadIdx.x;
    if(blockIdx.x == 4){
        __shared__ float sal[512], sar[512];
        sal[t] = al[t]; sal[t+256] = al[t+256];
        sar[t] = ar[t]; sar[t+256] = ar[t+256];
        __syncthreads();
        const float4* Wr = (const float4*)(W + t*512);
        float accl[8] = {0,0,0,0,0,0,0,0};
        float accr[8] = {0,0,0,0,0,0,0,0};
        for(int i = 0; i < 128; i++){
            float4 w = Wr[i];
            int o = 4*i;               // o = h*64 + d
            int h = o >> 6;
            const float* alp = &sal[o];
            const float* arp = &sar[o];
            accl[h] += w.x*alp[0] + w.y*alp[1] + w.z*alp[2] + w.w*alp[3];
            accr[h] += w.x*arp[0] + w.y*arp[1] + w.z*arp[2] + w.w*arp[3];
        }
        #pragma unroll
        for(int h = 0; h < 8; h++){ wl[h*256 + t] = accl[h]; wr[h*256 + t] = accr[h]; }
    } else {
        int b = blockIdx.x * 256 + t;
        if(b < Bb){
            int n = clampi(url[b] - 1, 0, Nn - 1);
            int old = atomicCAS(&uid[n], -1, -2);
            if(old == -1){
                int id = atomicAdd(cnt, 1);
                unode[id] = n;
                uid[n] = id;
            }
        }
    }
}

// K2: single edge pass: fixed 64-slot source lists per selected node
__global__ __launch_bounds__(256) void k_scatter(const int* __restrict__ src, const int* __restrict__ dst,
                                                 const int* __restrict__ uid, int* __restrict__ fill,
                                                 int* __restrict__ slist){
    int e = blockIdx.x * 256 + threadIdx.x;
    if(e >= Ee) return;
    int d = dst[e];
    if((unsigned)d >= (unsigned)Nn) return;
    int u = uid[d];
    if(u < 0) return;
    int pos = atomicAdd(&fill[u], 1);
    if(pos >= 64) return;             // P(deg>64 | Poisson(8)) ~ 1e-40
    slist[u*64 + pos] = clampi(src[e], 0, Nn - 1);
}

// K3: 2 nodes/block: per-edge el via wave-reduce (weights in REGISTERS),
// softmax, alpha-combine, dual GEMV.
__global__ __launch_bounds__(256) void k_gat(const float* __restrict__ features,
                                             const float* __restrict__ Wfc,
                                             const float* __restrict__ Wres,
                                             const float* __restrict__ bias,
                                             const float* __restrict__ wl,   // [8][256] transposed
                                             const float* __restrict__ wr,
                                             const int* __restrict__ cnt, const int* __restrict__ unode,
                                             const int* __restrict__ fill, const int* __restrict__ slist,
                                             float* __restrict__ gemb){
    int t = threadIdx.x;
    int lane = t & 63, wv = t >> 6;
    int cntv = cnt[0];
    int u0 = blockIdx.x * 2;
    if(u0 >= cntv) return;

    __shared__ float cxs[2][8][256];         // 16 KB
    __shared__ float fres[2][256];           //  2 KB
    __shared__ float sew[2][64][8];          //  4 KB: el per edge -> normalized alpha
    __shared__ float ser[2][8];
    __shared__ int   sslist[2][64];

    // per-lane weight slices in registers (fixed columns 4*lane..4*lane+3)
    float4 rwl[8], rwr[8];
    #pragma unroll
    for(int h = 0; h < 8; h++){
        rwl[h] = *(const float4*)&wl[h*256 + 4*lane];
        rwr[h] = *(const float4*)&wr[h*256 + 4*lane];
    }

    int dg[2];
    dg[0] = min(fill[u0], 64);
    dg[1] = (u0 + 1 < cntv) ? min(fill[u0 + 1], 64) : 0;
    #pragma unroll
    for(int j = 0; j < 2; j++){
        int u = u0 + j;
        if(t < dg[j]) sslist[j][t] = slist[u*64 + t];
        if(u < cntv) fres[j][t] = features[(size_t)unode[u] * FSz + t];
        else         fres[j][t] = 0.f;
    }
    __syncthreads();

    // ---- pass A: per-task wave-level dot products. tasks = edges (el) + 2 er rows
    int total = dg[0] + dg[1];
    for(int tau = wv; tau < total + 2; tau += 4){
        int j, i, s, isEr;
        if(tau < dg[0]){ j = 0; i = tau; s = sslist[0][i]; isEr = 0; }
        else if(tau < total){ j = 1; i = tau - dg[0]; s = sslist[1][i]; isEr = 0; }
        else { j = tau - total; i = 0; s = (u0 + j < cntv) ? unode[u0 + j] : 0; isEr = 1; }
        float4 x = *(const float4*)(features + (size_t)s * FSz + 4*lane);
        float p[8];
        if(isEr){                               // wave-uniform branch
            #pragma unroll
            for(int h = 0; h < 8; h++)
                p[h] = x.x*rwr[h].x + x.y*rwr[h].y + x.z*rwr[h].z + x.w*rwr[h].w;
        } else {
            #pragma unroll
            for(int h = 0; h < 8; h++)
                p[h] = x.x*rwl[h].x + x.y*rwl[h].y + x.z*rwl[h].z + x.w*rwl[h].w;
        }
        #pragma unroll
        for(int h = 0; h < 8; h++){
            #pragma unroll
            for(int m = 32; m >= 1; m >>= 1) p[h] += __shfl_xor(p[h], m, 64);
        }
        if(lane == 0){
            if(isEr){
                #pragma unroll
                for(int h = 0; h < 8; h++) ser[j][h] = p[h];
            } else {
                #pragma unroll
                for(int h = 0; h < 8; h++) sew[j][i][h] = p[h];
            }
        }
    }
    __syncthreads();
    // ---- softmax per (node, head): 16 threads, serial over deg (~8)
    if(t < 16){
        int j = t >> 3, h = t & 7;
        int dgj = dg[j];
        if(dgj > 0){
            float ern = ser[j][h];
            float m = -1e30f;
            for(int i = 0; i < dgj; i++){
                float v = sew[j][i][h] + ern;
                v = v > 0.f ? v : 0.2f * v;
                m = fmaxf(m, v);
            }
            float sum = 0.f;
            for(int i = 0; i < dgj; i++){
                float v = sew[j][i][h] + ern;
                v = v > 0.f ? v : 0.2f * v;
                float w = expf(v - m);
                sum += w;
                sew[j][i][h] = w;
            }
            float inv = 1.0f / fmaxf(sum, 1e-20f);
            for(int i = 0; i < dgj; i++) sew[j][i][h] *= inv;
        }
    }
    __syncthreads();
    // ---- pass B: alpha-combine source rows
    #pragma unroll
    for(int j = 0; j < 2; j++){
        float cx[8] = {0,0,0,0,0,0,0,0};
        for(int i = 0; i < dg[j]; i++){
            int s = sslist[j][i];
            float x = features[(size_t)s * FSz + t];
            const float* av = &sew[j][i][0];       // wave-uniform broadcast
            #pragma unroll
            for(int h = 0; h < 8; h++) cx[h] += av[h] * x;
        }
        #pragma unroll
        for(int h = 0; h < 8; h++) cxs[j][h][t] = cx[h];
    }
    __syncthreads();

    // ---- dual GEMV: thread owns output cols (2t, 2t+1); h = t>>5 half-wave-uniform
    int h = t >> 5;
    int o0 = 2 * t;
    const float2* Wfc2  = (const float2*)Wfc;
    const float2* Wres2 = (const float2*)Wres;
    float a00 = 0.f, a01 = 0.f, a10 = 0.f, a11 = 0.f;
    for(int f = 0; f < 256; f += 4){
        float2 w0 = Wfc2[(f+0)*256 + t];
        float2 w1 = Wfc2[(f+1)*256 + t];
        float2 w2 = Wfc2[(f+2)*256 + t];
        float2 w3 = Wfc2[(f+3)*256 + t];
        float2 r0 = Wres2[(f+0)*256 + t];
        float2 r1 = Wres2[(f+1)*256 + t];
        float2 r2 = Wres2[(f+2)*256 + t];
        float2 r3 = Wres2[(f+3)*256 + t];
        float4 c0 = *(const float4*)&cxs[0][h][f];
        float4 x0 = *(const float4*)&fres[0][f];
        float4 c1 = *(const float4*)&cxs[1][h][f];
        float4 x1 = *(const float4*)&fres[1][f];
        a00 += c0.x*w0.x + c0.y*w1.x + c0.z*w2.x + c0.w*w3.x + x0.x*r0.x + x0.y*r1.x + x0.z*r2.x + x0.w*r3.x;
        a01 += c0.x*w0.y + c0.y*w1.y + c0.z*w2.y + c0.w*w3.y + x0.x*r0.y + x0.y*r1.y + x0.z*r2.y + x0.w*r3.y;
        a10 += c1.x*w0.x + c1.y*w1.x + c1.z*w2.x + c1.w*w3.x + x1.x*r0.x + x1.y*r1.x + x1.z*r2.x + x1.w*r3.x;
        a11 += c1.x*w0.y + c1.y*w1.y + c1.z*w2.y + c1.w*w3.y + x1.x*r0.y + x1.y*r1.y + x1.z*r2.y + x1.w*r3.y;
    }
    float b0 = bias[o0], b1 = bias[o0 + 1];
    {
        float2* gp = (float2*)(gemb + (size_t)u0 * HD_);
        gp[t] = make_float2(a00 + b0, a01 + b1);
    }
    if(u0 + 1 < cntv){
        float2* gp = (float2*)(gemb + (size_t)(u0 + 1) * HD_);
        gp[t] = make_float2(a10 + b0, a11 + b1);
    }
}

// K4: per batch element. bf16 LDS (xn/q/k/ov), fp32 accum + fp32 residual.
// q,k,v fused in ONE projection loop (xnT read/unpacked once per d);
// v lives in registers through softmax. fc wave-split (no fcw redundancy).
__global__ __launch_bounds__(256, 4) void k_mha(const int* __restrict__ url, const int* __restrict__ uid,
                                             const float* __restrict__ gemb,
                                             const float* __restrict__ lng, const float* __restrict__ lnb,
                                             const float* __restrict__ wq, const float* __restrict__ wk,
                                             const float* __restrict__ wvp, const float* __restrict__ fcw,
                                             const float* __restrict__ fcb, const float* __restrict__ mlg,
                                             const float* __restrict__ mlb, const float* __restrict__ outw,
                                             const float* __restrict__ outb, float* __restrict__ out){
    __shared__ float A[512];                 // xr -> sc -> yy
    __shared__ float xnF[512];               // fp32 LN1 out (residual), [qq*64+dd]
    __shared__ unsigned short xnT[64*8];     // bf16 LN1 out, [d][qq]
    __shared__ unsigned short qkb[2*8*520];  // bf16 q | k ; later: ov (head) + fp32 partials (tail)
    __shared__ float mu8[8], rs8[8], pooled[64];

    int b = blockIdx.x, t = threadIdx.x;
    int lane = t & 63, wv = t >> 6;
    int n = clampi(url[b] - 1, 0, Nn - 1);
    int u = uid[n];
    if(u < 0) u = 0;
    const float* gp = gemb + (size_t)u * HD_;
    A[t] = gp[t]; A[t + 256] = gp[t + 256];
    __syncthreads();
    if(t < 8){
        float s = 0.f, s2 = 0.f;
        for(int d = 0; d < 64; d++){ float v = A[t*64 + d]; s += v; s2 += v * v; }
        float mu = s * (1.0f/64.0f);
        float var = s2 * (1.0f/64.0f) - mu * mu;
        mu8[t] = mu; rs8[t] = rsqrtf(fmaxf(var, 0.0f) + 1e-6f);
    }
    __syncthreads();
    #pragma unroll
    for(int p = 0; p < 2; p++){
        int i = p*256 + t; int q = i >> 6, d = i & 63;
        float xv = (A[i] - mu8[q]) * rs8[q] * lng[d] + lnb[d];
        xnF[i] = xv;
        xnT[d*8 + q] = f2bf(xv);
    }
    __syncthreads();
    // ---- fused q,k,v projection: thread owns cols t and t+256 ----
    float aq0[8] = {0,0,0,0,0,0,0,0}, aq1[8] = {0,0,0,0,0,0,0,0};
    float ak0[8] = {0,0,0,0,0,0,0,0}, ak1[8] = {0,0,0,0,0,0,0,0};
    float av0[8] = {0,0,0,0,0,0,0,0}, av1[8] = {0,0,0,0,0,0,0,0};
    #pragma unroll 2
    for(int d = 0; d < 64; d++){
        float q0 = wq[d*512 + t],  q1 = wq[d*512 + t + 256];
        float k0 = wk[d*512 + t],  k1 = wk[d*512 + t + 256];
        float v0 = wvp[d*512 + t], v1 = wvp[d*512 + t + 256];
        uint4 xp = *(const uint4*)&xnT[d*8];
        float xv[8] = { bflo(xp.x), bfhi(xp.x), bflo(xp.y), bfhi(xp.y),
                        bflo(xp.z), bfhi(xp.z), bflo(xp.w), bfhi(xp.w) };
        #pragma unroll
        for(int r = 0; r < 8; r++){
            aq0[r] += xv[r]*q0; aq1[r] += xv[r]*q1;
            ak0[r] += xv[r]*k0; ak1[r] += xv[r]*k1;
            av0[r] += xv[r]*v0; av1[r] += xv[r]*v1;
        }
    }
    #pragma unroll
    for(int qq = 0; qq < 8; qq++){
        qkb[qq*520 + t]              = f2bf(aq0[qq]);
        qkb[qq*520 + t + 256]        = f2bf(aq1[qq]);
        qkb[4160 + qq*520 + t]       = f2bf(ak0[qq]);
        qkb[4160 + qq*520 + t + 256] = f2bf(ak1[qq]);
    }
    __syncthreads();
    // ---- scores sc[nh*64 + qq*8 + kk] from bf16 q,k ----
    #pragma unroll
    for(int p = 0; p < 2; p++){
        int idx = p*256 + t;
        int nh = idx >> 6, qq = (idx >> 3) & 7, kk = idx & 7;
        const unsigned short* qrow = &qkb[qq*520 + nh*64];
        const unsigned short* krow = &qkb[4160 + kk*520 + nh*64];
        float s = 0.f;
        #pragma unroll
        for(int d8 = 0; d8 < 64; d8 += 8){
            uint4 qv = *(const uint4*)&qrow[d8];
            uint4 kv = *(const uint4*)&krow[d8];
            s += bflo(qv.x)*bflo(kv.x) + bfhi(qv.x)*bfhi(kv.x)
               + bflo(qv.y)*bflo(kv.y) + bfhi(qv.y)*bfhi(kv.y)
               + bflo(qv.z)*bflo(kv.z) + bfhi(qv.z)*bfhi(kv.z)
               + bflo(qv.w)*bflo(kv.w) + bfhi(qv.w)*bfhi(kv.w);
        }
        A[idx] = s * 0.125f;
    }
    __syncthreads();
    if(t < 64){
        float mx = -1e30f;
        #pragma unroll
        for(int k = 0; k < 8; k++) mx = fmaxf(mx, A[t*8 + k]);
        float e[8]; float s = 0.f;
        #pragma unroll
        for(int k = 0; k < 8; k++){ e[k] = expf(A[t*8 + k] - mx); s += e[k]; }
        float inv = 1.0f / s;
        #pragma unroll
        for(int k = 0; k < 8; k++) A[t*8 + k] = e[k] * inv;
    }
    __syncthreads();
    // ---- attn @ v (v in registers) -> ov (bf16) into q region (q,k dead) ----
    {
        int nh0 = wv;                        // col t -> nh0 ; col t+256 -> nh0+4
        #pragma unroll
        for(int qq = 0; qq < 8; qq++){
            const float* s0 = &A[nh0*64 + qq*8];
            const float* s1 = &A[(nh0+4)*64 + qq*8];
            float4 a0 = *(const float4*)s0, b0 = *(const float4*)(s0 + 4);
            float4 a1 = *(const float4*)s1, b1 = *(const float4*)(s1 + 4);
            float o0 = a0.x*av0[0] + a0.y*av0[1] + a0.z*av0[2] + a0.w*av0[3]
                     + b0.x*av0[4] + b0.y*av0[5] + b0.z*av0[6] + b0.w*av0[7];
            float o1 = a1.x*av1[0] + a1.y*av1[1] + a1.z*av1[2] + a1.w*av1[3]
                     + b1.x*av1[4] + b1.y*av1[5] + b1.z*av1[6] + b1.w*av1[7];
            qkb[qq*520 + t]       = f2bf(o0);
            qkb[qq*520 + t + 256] = f2bf(o1);
        }
    }
    __syncthreads();
    // ---- fc wave-split: wave wv owns k in [wv*128, wv*128+128) for ALL 512 outputs ----
    {
        float* P = (float*)&qkb[4160];       // 8 KB partials [4][512] (k region dead)
        int g = lane & 31;
        int qh = lane >> 5;                   // 0 or 1
        int k0 = wv * 128;
        float a[4][2] = {{0,0},{0,0},{0,0},{0,0}};
        const float2* fw2 = (const float2*)fcw;   // [512][32] float2
        for(int k = k0; k < k0 + 128; k += 8){
            float2 f0 = fw2[(k+0)*32 + g];
            float2 f1 = fw2[(k+1)*32 + g];
            float2 f2 = fw2[(k+2)*32 + g];
            float2 f3 = fw2[(k+3)*32 + g];
            float2 f4 = fw2[(k+4)*32 + g];
            float2 f5 = fw2[(k+5)*32 + g];
            float2 f6 = fw2[(k+6)*32 + g];
            float2 f7 = fw2[(k+7)*32 + g];
            #pragma unroll
            for(int jq = 0; jq < 4; jq++){
                int qq = qh*4 + jq;
                uint4 op = *(const uint4*)&qkb[qq*520 + k];   // 8 bf16 ov values
                float x0 = bflo(op.x), x1 = bfhi(op.x), x2 = bflo(op.y), x3 = bfhi(op.y);
                float x4 = bflo(op.z), x5 = bfhi(op.z), x6 = bflo(op.w), x7 = bfhi(op.w);
                a[jq][0] += x0*f0.x + x1*f1.x + x2*f2.x + x3*f3.x + x4*f4.x + x5*f5.x + x6*f6.x + x7*f7.x;
                a[jq][1] += x0*f0.y + x1*f1.y + x2*f2.y + x3*f3.y + x4*f4.y + x5*f5.y + x6*f6.y + x7*f7.y;
            }
        }
        __syncthreads();   // order P writes (k region) after all score/ov traffic settled
        #pragma unroll
        for(int jq = 0; jq < 4; jq++){
            int qq = qh*4 + jq;
            *(float2*)&P[wv*512 + qq*64 + 2*g] = make_float2(a[jq][0], a[jq][1]);
        }
        __syncthreads();
        // combine partials + bias + fp32 residual -> yy in A (sc dead after attn)
        #pragma unroll
        for(int p = 0; p < 2; p++){
            int o = p*256 + t;
            int dd = o & 63;
            A[o] = P[o] + P[512 + o] + P[1024 + o] + P[1536 + o] + fcb[dd] + xnF[o];
        }
    }
    __syncthreads();
    if(t < 8){
        float s = 0.f, s2 = 0.f;
        for(int d = 0; d < 64; d++){ float v = A[t*64 + d]; s += v; s2 += v * v; }
        float mu = s * (1.0f/64.0f);
        float var = s2 * (1.0f/64.0f) - mu * mu;
        mu8[t] = mu; rs8[t] = rsqrtf(fmaxf(var, 0.0f) + 1e-6f);
    }
    __syncthreads();
    if(t < 64){
        float g2 = mlg[t], bb = mlb[t];
        float s = 0.f;
        #pragma unroll
        for(int qq = 0; qq < 8; qq++)
            s += (A[qq*64 + t] - mu8[qq]) * rs8[qq] * g2 + bb;
        pooled[t] = s;
    }
    __syncthreads();
    if(t < 2){
        float s = outb[t];
        for(int d = 0; d < 64; d++) s += pooled[d] * outw[d*2 + t];
        out[b*2 + t] = s;
    }
}

extern "C" void kernel_launch(void* const* d_in, const int* in_sizes, int n_in,
                              void* d_out, int out_size, void* d_ws, size_t ws_size,
                              hipStream_t stream){
    (void)in_sizes; (void)n_in; (void)out_size; (void)ws_size;
    const float* features  = (const float*)d_in[0];
    const int*   src       = (const int*)d_in[1];
    const int*   dst       = (const int*)d_in[2];
    const int*   url       = (const int*)d_in[3];
    const float* gat_fc_w  = (const float*)d_in[4];
    const float* attn_l    = (const float*)d_in[5];
    const float* attn_r    = (const float*)d_in[6];
    const float* gat_res_w = (const float*)d_in[7];
    const float* gat_bias  = (const float*)d_in[8];
    const float* ln_g      = (const float*)d_in[9];
    const float* ln_b      = (const float*)d_in[10];
    const float* wq        = (const float*)d_in[11];
    const float* wk        = (const float*)d_in[12];
    const float* wv        = (const float*)d_in[13];
    const float* fc_w      = (const float*)d_in[14];
    const float* fc_b      = (const float*)d_in[15];
    const float* mha_ln_g  = (const float*)d_in[16];
    const float* mha_ln_b  = (const float*)d_in[17];
    const float* out_w     = (const float*)d_in[18];
    const float* out_b     = (const float*)d_in[19];

    char* base = (char*)d_ws;
    size_t cur = 0;
    auto alloc = [&](size_t nbytes) -> void* {
        void* p = base + cur;
        cur = (cur + nbytes + 255) & ~(size_t)255;
        return p;
    };
    float* wl    = (float*)alloc(2048 * sizeof(float));   // transposed [8][256]
    float* wr    = (float*)alloc(2048 * sizeof(float));
    int*   uid   = (int*)alloc((size_t)Nn * sizeof(int));
    int*   unode = (int*)alloc(1024 * sizeof(int));
    int*   fill  = (int*)alloc(1056 * sizeof(int));       // fill[0..1023], cnt = &fill[1024]
    int*   cnt   = fill + 1024;
    int*   slist = (int*)alloc((size_t)1024 * 64 * sizeof(int));
    float* gemb  = (float*)alloc((size_t)1024 * 512 * sizeof(float));

    // init via async memsets (graph-safe): uid = -1 (0xFF bytes), fill+cnt = 0
    hipMemsetAsync(uid, 0xFF, (size_t)Nn * sizeof(int), stream);
    hipMemsetAsync(fill, 0, 1056 * sizeof(int), stream);

    hipLaunchKernelGGL(k_mark,    dim3(5),    dim3(256), 0, stream, url, uid, unode, cnt,
                       gat_fc_w, attn_l, attn_r, wl, wr);
    hipLaunchKernelGGL(k_scatter, dim3(1563), dim3(256), 0, stream, src, dst, uid, fill, slist);
    hipLaunchKernelGGL(k_gat,     dim3(512),  dim3(256), 0, stream, features, gat_fc_w, gat_res_w, gat_bias,
                       wl, wr, cnt, unode, fill, slist, gemb);
    hipLaunchKernelGGL(k_mha,     dim3(1024), dim3(256), 0, stream, url, uid, gemb, ln_g, ln_b,
                       wq, wk, wv, fc_w, fc_b, mha_ln_g, mha_ln_b, out_w, out_b,
                       (float*)d_out);
}

// Round 12
// 220.928 us; speedup vs baseline: 6.5065x; 1.0782x over previous
//
#include <hip/hip_runtime.h>
#include <math.h>

#define Nn 50000
#define Ee 400000
#define FSz 256
#define HD_ 512
#define Bb 1024

// World model (settled R5/R6): ALL float inputs fp32; OUTPUT fp32.
static __device__ __forceinline__ int clampi(int v, int lo, int hi){
    return v < lo ? lo : (v > hi ? hi : v);
}
static __device__ __forceinline__ unsigned short f2bf(float f){
    unsigned int u = __float_as_uint(f);
    unsigned int r = u + 0x7FFFu + ((u >> 16) & 1u);
    return (unsigned short)(r >> 16);
}
static __device__ __forceinline__ float bflo(unsigned int v){ return __uint_as_float(v << 16); }
static __device__ __forceinline__ float bfhi(unsigned int v){ return __uint_as_float(v & 0xFFFF0000u); }

// K1: blocks 0-3: assign dense ids to unique selected nodes.
//     blocks 4-19: parallel fold attn_l/attn_r into gat_fc_w -> wl,wr [8][256]
//     (wave-per-row, 4 rows/wave — was a single-block ~40 µs serial stall).
__global__ __launch_bounds__(256) void k_mark(const int* __restrict__ url, int* uid, int* unode, int* cnt,
                                              const float* __restrict__ W,
                                              const float* __restrict__ al,
                                              const float* __restrict__ ar,
                                              float* __restrict__ wl, float* __restrict__ wr){
    int t = threadIdx.x;
    if(blockIdx.x >= 4){
        int bi = blockIdx.x - 4;          // 0..15
        int wv = t >> 6, lane = t & 63;
        #pragma unroll
        for(int r = 0; r < 4; r++){
            int f = bi*16 + wv*4 + r;     // 16 blocks x 4 waves x 4 rows = 256
            float pl[8], pr[8];
            #pragma unroll
            for(int h = 0; h < 8; h++){
                float w = W[f*512 + h*64 + lane];     // coalesced per segment
                pl[h] = w * al[h*64 + lane];
                pr[h] = w * ar[h*64 + lane];
            }
            #pragma unroll
            for(int h = 0; h < 8; h++){
                #pragma unroll
                for(int m = 32; m >= 1; m >>= 1){
                    pl[h] += __shfl_xor(pl[h], m, 64);
                    pr[h] += __shfl_xor(pr[h], m, 64);
                }
            }
            #pragma unroll
            for(int h = 0; h < 8; h++){
                if(lane == h){ wl[h*256 + f] = pl[h]; wr[h*256 + f] = pr[h]; }
            }
        }
    } else {
        int b = blockIdx.x * 256 + t;
        if(b < Bb){
            int n = clampi(url[b] - 1, 0, Nn - 1);
            int old = atomicCAS(&uid[n], -1, -2);
            if(old == -1){
                int id = atomicAdd(cnt, 1);
                unode[id] = n;
                uid[n] = id;
            }
        }
    }
}

// K2: single edge pass: fixed 64-slot source lists per selected node
__global__ __launch_bounds__(256) void k_scatter(const int* __restrict__ src, const int* __restrict__ dst,
                                                 const int* __restrict__ uid, int* __restrict__ fill,
                                                 int* __restrict__ slist){
    int e = blockIdx.x * 256 + threadIdx.x;
    if(e >= Ee) return;
    int d = dst[e];
    if((unsigned)d >= (unsigned)Nn) return;
    int u = uid[d];
    if(u < 0) return;
    int pos = atomicAdd(&fill[u], 1);
    if(pos >= 64) return;             // P(deg>64 | Poisson(8)) ~ 1e-40
    slist[u*64 + pos] = clampi(src[e], 0, Nn - 1);
}

// K3: 4 nodes/block (halves GEMV L2 weight traffic vs 2): per-edge el via
// wave-reduce (weights in registers), softmax, alpha-combine (i-outer for
// 4 concurrent gathers), quad GEMV.
__global__ __launch_bounds__(256) void k_gat(const float* __restrict__ features,
                                             const float* __restrict__ Wfc,
                                             const float* __restrict__ Wres,
                                             const float* __restrict__ bias,
                                             const float* __restrict__ wl,   // [8][256] transposed
                                             const float* __restrict__ wr,
                                             const int* __restrict__ cnt, const int* __restrict__ unode,
                                             const int* __restrict__ fill, const int* __restrict__ slist,
                                             float* __restrict__ gemb){
    int t = threadIdx.x;
    int lane = t & 63, wv = t >> 6;
    int cntv = cnt[0];
    int u0 = blockIdx.x * 4;
    if(u0 >= cntv) return;

    __shared__ float cxs[4][8][256];         // 32 KB
    __shared__ float fres[4][256];           //  4 KB
    __shared__ float sew[4][64][8];          //  8 KB: el per edge -> normalized alpha
    __shared__ float ser[4][8];
    __shared__ int   sslist[4][64];

    // zero-init sew (masked-lane reads in pass B must see 0, not stale LDS)
    for(int i = t; i < 4*64*8; i += 256) ((float*)sew)[i] = 0.f;

    // per-lane weight slices in registers (fixed columns 4*lane..4*lane+3)
    float4 rwl[8], rwr[8];
    #pragma unroll
    for(int h = 0; h < 8; h++){
        rwl[h] = *(const float4*)&wl[h*256 + 4*lane];
        rwr[h] = *(const float4*)&wr[h*256 + 4*lane];
    }

    int dg[4];
    #pragma unroll
    for(int j = 0; j < 4; j++){
        int u = u0 + j;
        dg[j] = (u < cntv) ? min(fill[u], 64) : 0;
        if(t < dg[j]) sslist[j][t] = slist[u*64 + t];
        if(u < cntv) fres[j][t] = features[(size_t)unode[u] * FSz + t];
        else         fres[j][t] = 0.f;
    }
    __syncthreads();

    // ---- pass A: wave-level dot products; tasks = all edges + 4 er rows
    int c1 = dg[0], c2 = c1 + dg[1], c3 = c2 + dg[2];
    int total = c3 + dg[3];
    for(int tau = wv; tau < total + 4; tau += 4){
        int j, i, isEr = 0;
        if(tau < c1){ j = 0; i = tau; }
        else if(tau < c2){ j = 1; i = tau - c1; }
        else if(tau < c3){ j = 2; i = tau - c2; }
        else if(tau < total){ j = 3; i = tau - c3; }
        else { j = tau - total; i = 0; isEr = 1; }
        int s = isEr ? ((u0 + j < cntv) ? unode[u0 + j] : 0) : sslist[j][i];
        float4 x = *(const float4*)(features + (size_t)s * FSz + 4*lane);
        float p[8];
        if(isEr){
            #pragma unroll
            for(int h = 0; h < 8; h++)
                p[h] = x.x*rwr[h].x + x.y*rwr[h].y + x.z*rwr[h].z + x.w*rwr[h].w;
        } else {
            #pragma unroll
            for(int h = 0; h < 8; h++)
                p[h] = x.x*rwl[h].x + x.y*rwl[h].y + x.z*rwl[h].z + x.w*rwl[h].w;
        }
        #pragma unroll
        for(int h = 0; h < 8; h++){
            #pragma unroll
            for(int m = 32; m >= 1; m >>= 1) p[h] += __shfl_xor(p[h], m, 64);
        }
        if(lane == 0){
            if(isEr){
                #pragma unroll
                for(int h = 0; h < 8; h++) ser[j][h] = p[h];
            } else {
                #pragma unroll
                for(int h = 0; h < 8; h++) sew[j][i][h] = p[h];
            }
        }
    }
    __syncthreads();
    // ---- softmax per (node, head): 32 threads, serial over deg (~8)
    if(t < 32){
        int j = t >> 3, h = t & 7;
        int dgj = dg[j];
        if(dgj > 0){
            float ern = ser[j][h];
            float m = -1e30f;
            for(int i = 0; i < dgj; i++){
                float v = sew[j][i][h] + ern;
                v = v > 0.f ? v : 0.2f * v;
                m = fmaxf(m, v);
            }
            float sum = 0.f;
            for(int i = 0; i < dgj; i++){
                float v = sew[j][i][h] + ern;
                v = v > 0.f ? v : 0.2f * v;
                float w = expf(v - m);
                sum += w;
                sew[j][i][h] = w;
            }
            float inv = 1.0f / fmaxf(sum, 1e-20f);
            for(int i = 0; i < dgj; i++) sew[j][i][h] *= inv;
        }
    }
    __syncthreads();
    // ---- pass B: alpha-combine; i-outer so 4 node-gathers are in flight
    {
        float cx[4][8];
        #pragma unroll
        for(int j = 0; j < 4; j++)
            #pragma unroll
            for(int h = 0; h < 8; h++) cx[j][h] = 0.f;
        int mxd = max(max(dg[0], dg[1]), max(dg[2], dg[3]));
        for(int i = 0; i < mxd; i++){
            float x[4];
            #pragma unroll
            for(int j = 0; j < 4; j++){
                int s = (i < dg[j]) ? sslist[j][i] : 0;     // safe row; alpha=0 kills it
                x[j] = features[(size_t)s * FSz + t];
            }
            #pragma unroll
            for(int j = 0; j < 4; j++){
                const float* av = &sew[j][i][0];            // 0 for masked (zero-init)
                float xm = (i < dg[j]) ? x[j] : 0.f;
                #pragma unroll
                for(int h = 0; h < 8; h++) cx[j][h] += av[h] * xm;
            }
        }
        #pragma unroll
        for(int j = 0; j < 4; j++)
            #pragma unroll
            for(int h = 0; h < 8; h++) cxs[j][h][t] = cx[j][h];
    }
    __syncthreads();

    // ---- quad GEMV: thread owns output cols (2t, 2t+1); h = t>>5 half-wave-uniform
    int h = t >> 5;
    int o0 = 2 * t;
    const float2* Wfc2  = (const float2*)Wfc;
    const float2* Wres2 = (const float2*)Wres;
    float a[4][2] = {{0,0},{0,0},{0,0},{0,0}};
    for(int f = 0; f < 256; f += 4){
        float2 w0 = Wfc2[(f+0)*256 + t];
        float2 w1 = Wfc2[(f+1)*256 + t];
        float2 w2 = Wfc2[(f+2)*256 + t];
        float2 w3 = Wfc2[(f+3)*256 + t];
        float2 r0 = Wres2[(f+0)*256 + t];
        float2 r1 = Wres2[(f+1)*256 + t];
        float2 r2 = Wres2[(f+2)*256 + t];
        float2 r3 = Wres2[(f+3)*256 + t];
        #pragma unroll
        for(int j = 0; j < 4; j++){
            float4 c = *(const float4*)&cxs[j][h][f];
            float4 x = *(const float4*)&fres[j][f];
            a[j][0] += c.x*w0.x + c.y*w1.x + c.z*w2.x + c.w*w3.x
                     + x.x*r0.x + x.y*r1.x + x.z*r2.x + x.w*r3.x;
            a[j][1] += c.x*w0.y + c.y*w1.y + c.z*w2.y + c.w*w3.y
                     + x.x*r0.y + x.y*r1.y + x.z*r2.y + x.w*r3.y;
        }
    }
    float b0 = bias[o0], b1 = bias[o0 + 1];
    #pragma unroll
    for(int j = 0; j < 4; j++){
        if(u0 + j < cntv){
            float2* gp = (float2*)(gemb + (size_t)(u0 + j) * HD_);
            gp[t] = make_float2(a[j][0] + b0, a[j][1] + b1);
        }
    }
}

// K4: per batch element. bf16 LDS (xn/q/k/ov), fp32 accum + fp32 residual.
// q,k,v fused in ONE projection loop; v in registers through softmax.
// fc wave-split (no fcw redundancy). UNCHANGED from R11 (53.7 µs).
__global__ __launch_bounds__(256, 4) void k_mha(const int* __restrict__ url, const int* __restrict__ uid,
                                             const float* __restrict__ gemb,
                                             const float* __restrict__ lng, const float* __restrict__ lnb,
                                             const float* __restrict__ wq, const float* __restrict__ wk,
                                             const float* __restrict__ wvp, const float* __restrict__ fcw,
                                             const float* __restrict__ fcb, const float* __restrict__ mlg,
                                             const float* __restrict__ mlb, const float* __restrict__ outw,
                                             const float* __restrict__ outb, float* __restrict__ out){
    __shared__ float A[512];                 // xr -> sc -> yy
    __shared__ float xnF[512];               // fp32 LN1 out (residual), [qq*64+dd]
    __shared__ unsigned short xnT[64*8];     // bf16 LN1 out, [d][qq]
    __shared__ unsigned short qkb[2*8*520];  // bf16 q | k ; later: ov (head) + fp32 partials (tail)
    __shared__ float mu8[8], rs8[8], pooled[64];

    int b = blockIdx.x, t = threadIdx.x;
    int lane = t & 63, wv = t >> 6;
    int n = clampi(url[b] - 1, 0, Nn - 1);
    int u = uid[n];
    if(u < 0) u = 0;
    const float* gp = gemb + (size_t)u * HD_;
    A[t] = gp[t]; A[t + 256] = gp[t + 256];
    __syncthreads();
    if(t < 8){
        float s = 0.f, s2 = 0.f;
        for(int d = 0; d < 64; d++){ float v = A[t*64 + d]; s += v; s2 += v * v; }
        float mu = s * (1.0f/64.0f);
        float var = s2 * (1.0f/64.0f) - mu * mu;
        mu8[t] = mu; rs8[t] = rsqrtf(fmaxf(var, 0.0f) + 1e-6f);
    }
    __syncthreads();
    #pragma unroll
    for(int p = 0; p < 2; p++){
        int i = p*256 + t; int q = i >> 6, d = i & 63;
        float xv = (A[i] - mu8[q]) * rs8[q] * lng[d] + lnb[d];
        xnF[i] = xv;
        xnT[d*8 + q] = f2bf(xv);
    }
    __syncthreads();
    // ---- fused q,k,v projection: thread owns cols t and t+256 ----
    float aq0[8] = {0,0,0,0,0,0,0,0}, aq1[8] = {0,0,0,0,0,0,0,0};
    float ak0[8] = {0,0,0,0,0,0,0,0}, ak1[8] = {0,0,0,0,0,0,0,0};
    float av0[8] = {0,0,0,0,0,0,0,0}, av1[8] = {0,0,0,0,0,0,0,0};
    #pragma unroll 2
    for(int d = 0; d < 64; d++){
        float q0 = wq[d*512 + t],  q1 = wq[d*512 + t + 256];
        float k0 = wk[d*512 + t],  k1 = wk[d*512 + t + 256];
        float v0 = wvp[d*512 + t], v1 = wvp[d*512 + t + 256];
        uint4 xp = *(const uint4*)&xnT[d*8];
        float xv[8] = { bflo(xp.x), bfhi(xp.x), bflo(xp.y), bfhi(xp.y),
                        bflo(xp.z), bfhi(xp.z), bflo(xp.w), bfhi(xp.w) };
        #pragma unroll
        for(int r = 0; r < 8; r++){
            aq0[r] += xv[r]*q0; aq1[r] += xv[r]*q1;
            ak0[r] += xv[r]*k0; ak1[r] += xv[r]*k1;
            av0[r] += xv[r]*v0; av1[r] += xv[r]*v1;
        }
    }
    #pragma unroll
    for(int qq = 0; qq < 8; qq++){
        qkb[qq*520 + t]              = f2bf(aq0[qq]);
        qkb[qq*520 + t + 256]        = f2bf(aq1[qq]);
        qkb[4160 + qq*520 + t]       = f2bf(ak0[qq]);
        qkb[4160 + qq*520 + t + 256] = f2bf(ak1[qq]);
    }
    __syncthreads();
    // ---- scores sc[nh*64 + qq*8 + kk] from bf16 q,k ----
    #pragma unroll
    for(int p = 0; p < 2; p++){
        int idx = p*256 + t;
        int nh = idx >> 6, qq = (idx >> 3) & 7, kk = idx & 7;
        const unsigned short* qrow = &qkb[qq*520 + nh*64];
        const unsigned short* krow = &qkb[4160 + kk*520 + nh*64];
        float s = 0.f;
        #pragma unroll
        for(int d8 = 0; d8 < 64; d8 += 8){
            uint4 qv = *(const uint4*)&qrow[d8];
            uint4 kv = *(const uint4*)&krow[d8];
            s += bflo(qv.x)*bflo(kv.x) + bfhi(qv.x)*bfhi(kv.x)
               + bflo(qv.y)*bflo(kv.y) + bfhi(qv.y)*bfhi(kv.y)
               + bflo(qv.z)*bflo(kv.z) + bfhi(qv.z)*bfhi(kv.z)
               + bflo(qv.w)*bflo(kv.w) + bfhi(qv.w)*bfhi(kv.w);
        }
        A[idx] = s * 0.125f;
    }
    __syncthreads();
    if(t < 64){
        float mx = -1e30f;
        #pragma unroll
        for(int k = 0; k < 8; k++) mx = fmaxf(mx, A[t*8 + k]);
        float e[8]; float s = 0.f;
        #pragma unroll
        for(int k = 0; k < 8; k++){ e[k] = expf(A[t*8 + k] - mx); s += e[k]; }
        float inv = 1.0f / s;
        #pragma unroll
        for(int k = 0; k < 8; k++) A[t*8 + k] = e[k] * inv;
    }
    __syncthreads();
    // ---- attn @ v (v in registers) -> ov (bf16) into q region (q,k dead) ----
    {
        int nh0 = wv;                        // col t -> nh0 ; col t+256 -> nh0+4
        #pragma unroll
        for(int qq = 0; qq < 8; qq++){
            const float* s0 = &A[nh0*64 + qq*8];
            const float* s1 = &A[(nh0+4)*64 + qq*8];
            float4 a0 = *(const float4*)s0, b0 = *(const float4*)(s0 + 4);
            float4 a1 = *(const float4*)s1, b1 = *(const float4*)(s1 + 4);
            float o0 = a0.x*av0[0] + a0.y*av0[1] + a0.z*av0[2] + a0.w*av0[3]
                     + b0.x*av0[4] + b0.y*av0[5] + b0.z*av0[6] + b0.w*av0[7];
            float o1 = a1.x*av1[0] + a1.y*av1[1] + a1.z*av1[2] + a1.w*av1[3]
                     + b1.x*av1[4] + b1.y*av1[5] + b1.z*av1[6] + b1.w*av1[7];
            qkb[qq*520 + t]       = f2bf(o0);
            qkb[qq*520 + t + 256] = f2bf(o1);
        }
    }
    __syncthreads();
    // ---- fc wave-split: wave wv owns k in [wv*128, wv*128+128) for ALL 512 outputs ----
    {
        float* P = (float*)&qkb[4160];       // 8 KB partials [4][512] (k region dead)
        int g = lane & 31;
        int qh = lane >> 5;                   // 0 or 1
        int k0 = wv * 128;
        float a[4][2] = {{0,0},{0,0},{0,0},{0,0}};
        const float2* fw2 = (const float2*)fcw;   // [512][32] float2
        for(int k = k0; k < k0 + 128; k += 8){
            float2 f0 = fw2[(k+0)*32 + g];
            float2 f1 = fw2[(k+1)*32 + g];
            float2 f2 = fw2[(k+2)*32 + g];
            float2 f3 = fw2[(k+3)*32 + g];
            float2 f4 = fw2[(k+4)*32 + g];
            float2 f5 = fw2[(k+5)*32 + g];
            float2 f6 = fw2[(k+6)*32 + g];
            float2 f7 = fw2[(k+7)*32 + g];
            #pragma unroll
            for(int jq = 0; jq < 4; jq++){
                int qq = qh*4 + jq;
                uint4 op = *(const uint4*)&qkb[qq*520 + k];   // 8 bf16 ov values
                float x0 = bflo(op.x), x1 = bfhi(op.x), x2 = bflo(op.y), x3 = bfhi(op.y);
                float x4 = bflo(op.z), x5 = bfhi(op.z), x6 = bflo(op.w), x7 = bfhi(op.w);
                a[jq][0] += x0*f0.x + x1*f1.x + x2*f2.x + x3*f3.x + x4*f4.x + x5*f5.x + x6*f6.x + x7*f7.x;
                a[jq][1] += x0*f0.y + x1*f1.y + x2*f2.y + x3*f3.y + x4*f4.y + x5*f5.y + x6*f6.y + x7*f7.y;
            }
        }
        __syncthreads();
        #pragma unroll
        for(int jq = 0; jq < 4; jq++){
            int qq = qh*4 + jq;
            *(float2*)&P[wv*512 + qq*64 + 2*g] = make_float2(a[jq][0], a[jq][1]);
        }
        __syncthreads();
        #pragma unroll
        for(int p = 0; p < 2; p++){
            int o = p*256 + t;
            int dd = o & 63;
            A[o] = P[o] + P[512 + o] + P[1024 + o] + P[1536 + o] + fcb[dd] + xnF[o];
        }
    }
    __syncthreads();
    if(t < 8){
        float s = 0.f, s2 = 0.f;
        for(int d = 0; d < 64; d++){ float v = A[t*64 + d]; s += v; s2 += v * v; }
        float mu = s * (1.0f/64.0f);
        float var = s2 * (1.0f/64.0f) - mu * mu;
        mu8[t] = mu; rs8[t] = rsqrtf(fmaxf(var, 0.0f) + 1e-6f);
    }
    __syncthreads();
    if(t < 64){
        float g2 = mlg[t], bb = mlb[t];
        float s = 0.f;
        #pragma unroll
        for(int qq = 0; qq < 8; qq++)
            s += (A[qq*64 + t] - mu8[qq]) * rs8[qq] * g2 + bb;
        pooled[t] = s;
    }
    __syncthreads();
    if(t < 2){
        float s = outb[t];
        for(int d = 0; d < 64; d++) s += pooled[d] * outw[d*2 + t];
        out[b*2 + t] = s;
    }
}

extern "C" void kernel_launch(void* const* d_in, const int* in_sizes, int n_in,
                              void* d_out, int out_size, void* d_ws, size_t ws_size,
                              hipStream_t stream){
    (void)in_sizes; (void)n_in; (void)out_size; (void)ws_size;
    const float* features  = (const float*)d_in[0];
    const int*   src       = (const int*)d_in[1];
    const int*   dst       = (const int*)d_in[2];
    const int*   url       = (const int*)d_in[3];
    const float* gat_fc_w  = (const float*)d_in[4];
    const float* attn_l    = (const float*)d_in[5];
    const float* attn_r    = (const float*)d_in[6];
    const float* gat_res_w = (const float*)d_in[7];
    const float* gat_bias  = (const float*)d_in[8];
    const float* ln_g      = (const float*)d_in[9];
    const float* ln_b      = (const float*)d_in[10];
    const float* wq        = (const float*)d_in[11];
    const float* wk        = (const float*)d_in[12];
    const float* wv        = (const float*)d_in[13];
    const float* fc_w      = (const float*)d_in[14];
    const float* fc_b      = (const float*)d_in[15];
    const float* mha_ln_g  = (const float*)d_in[16];
    const float* mha_ln_b  = (const float*)d_in[17];
    const float* out_w     = (const float*)d_in[18];
    const float* out_b     = (const float*)d_in[19];

    char* base = (char*)d_ws;
    size_t cur = 0;
    auto alloc = [&](size_t nbytes) -> void* {
        void* p = base + cur;
        cur = (cur + nbytes + 255) & ~(size_t)255;
        return p;
    };
    float* wl    = (float*)alloc(2048 * sizeof(float));   // transposed [8][256]
    float* wr    = (float*)alloc(2048 * sizeof(float));
    int*   uid   = (int*)alloc((size_t)Nn * sizeof(int));
    int*   unode = (int*)alloc(1024 * sizeof(int));
    int*   fill  = (int*)alloc(1056 * sizeof(int));       // fill[0..1023], cnt = &fill[1024]
    int*   cnt   = fill + 1024;
    int*   slist = (int*)alloc((size_t)1024 * 64 * sizeof(int));
    float* gemb  = (float*)alloc((size_t)1024 * 512 * sizeof(float));

    // init via async memsets (graph-safe): uid = -1 (0xFF bytes), fill+cnt = 0
    hipMemsetAsync(uid, 0xFF, (size_t)Nn * sizeof(int), stream);
    hipMemsetAsync(fill, 0, 1056 * sizeof(int), stream);

    hipLaunchKernelGGL(k_mark,    dim3(20),   dim3(256), 0, stream, url, uid, unode, cnt,
                       gat_fc_w, attn_l, attn_r, wl, wr);
    hipLaunchKernelGGL(k_scatter, dim3(1563), dim3(256), 0, stream, src, dst, uid, fill, slist);
    hipLaunchKernelGGL(k_gat,     dim3(256),  dim3(256), 0, stream, features, gat_fc_w, gat_res_w, gat_bias,
                       wl, wr, cnt, unode, fill, slist, gemb);
    hipLaunchKernelGGL(k_mha,     dim3(1024), dim3(256), 0, stream, url, uid, gemb, ln_g, ln_b,
                       wq, wk, wv, fc_w, fc_b, mha_ln_g, mha_ln_b, out_w, out_b,
                       (float*)d_out);
}

// Round 13
// 210.727 us; speedup vs baseline: 6.8214x; 1.0484x over previous
//
#include <hip/hip_runtime.h>
#include <math.h>

#define Nn 50000
#define Ee 400000
#define FSz 256
#define HD_ 512
#define Bb 1024
#define HSZ 2048

// World model (settled R5/R6): ALL float inputs fp32; OUTPUT fp32.
static __device__ __forceinline__ int clampi(int v, int lo, int hi){
    return v < lo ? lo : (v > hi ? hi : v);
}
static __device__ __forceinline__ unsigned short f2bf(float f){
    unsigned int u = __float_as_uint(f);
    unsigned int r = u + 0x7FFFu + ((u >> 16) & 1u);
    return (unsigned short)(r >> 16);
}
static __device__ __forceinline__ float bflo(unsigned int v){ return __uint_as_float(v << 16); }
static __device__ __forceinline__ float bfhi(unsigned int v){ return __uint_as_float(v & 0xFFFF0000u); }

// K1: blocks 0-1562: edge scatter via per-block LDS hash of url (node -> chain
//     of batch slots). Replaces the old global-uid pass entirely.
//     blocks 1563-1578: parallel fold attn_l/attn_r -> wl,wr [8][256].
__global__ __launch_bounds__(256) void k_scatter(const int* __restrict__ src, const int* __restrict__ dst,
                                                 const int* __restrict__ url,
                                                 int* __restrict__ fill, int* __restrict__ slist,
                                                 const float* __restrict__ W,
                                                 const float* __restrict__ al,
                                                 const float* __restrict__ ar,
                                                 float* __restrict__ wl, float* __restrict__ wr){
    int t = threadIdx.x;
    if(blockIdx.x >= 1563){
        int bi = blockIdx.x - 1563;       // 0..15
        int wv = t >> 6, lane = t & 63;
        #pragma unroll
        for(int r = 0; r < 4; r++){
            int f = bi*16 + wv*4 + r;     // 16 blocks x 4 waves x 4 rows = 256
            float pl[8], pr[8];
            #pragma unroll
            for(int h = 0; h < 8; h++){
                float w = W[f*512 + h*64 + lane];
                pl[h] = w * al[h*64 + lane];
                pr[h] = w * ar[h*64 + lane];
            }
            #pragma unroll
            for(int h = 0; h < 8; h++){
                #pragma unroll
                for(int m = 32; m >= 1; m >>= 1){
                    pl[h] += __shfl_xor(pl[h], m, 64);
                    pr[h] += __shfl_xor(pr[h], m, 64);
                }
            }
            #pragma unroll
            for(int h = 0; h < 8; h++){
                if(lane == h){ wl[h*256 + f] = pl[h]; wr[h*256 + f] = pr[h]; }
            }
        }
        return;
    }
    __shared__ int key[HSZ];        // node id or -1
    __shared__ int chainhead[HSZ];  // batch-slot chain head or -1
    __shared__ short nxt[Bb];       // next slot with same node (-1 terminal)
    for(int i = t; i < HSZ; i += 256){ key[i] = -1; chainhead[i] = -1; }
    __syncthreads();
    // build: every block constructs the same node->slots map (set-deterministic)
    for(int b = t; b < Bb; b += 256){
        int n = clampi(url[b] - 1, 0, Nn - 1);
        int h = n & (HSZ - 1);
        while(true){
            int prev = atomicCAS(&key[h], -1, n);
            if(prev == -1 || prev == n) break;
            h = (h + 1) & (HSZ - 1);
        }
        int old = atomicExch(&chainhead[h], b);
        nxt[b] = (short)old;
    }
    __syncthreads();
    int e = blockIdx.x * 256 + t;
    if(e >= Ee) return;
    int d = dst[e];
    if((unsigned)d >= (unsigned)Nn) return;
    int h = d & (HSZ - 1);
    while(true){
        int k = key[h];
        if(k == -1) return;           // node not selected
        if(k == d) break;
        h = (h + 1) & (HSZ - 1);
    }
    int s = clampi(src[e], 0, Nn - 1);
    for(int b = chainhead[h]; b != -1; b = nxt[b]){
        int pos = atomicAdd(&fill[b], 1);
        if(pos < 64) slist[b*64 + pos] = s;   // P(deg>64 | Poisson(8)) ~ 1e-40
    }
}

// K3: 4 slots/block: per-edge el via wave-reduce (weights in registers),
// softmax, alpha-combine, quad GEMV. Slot-based (duplicates recomputed).
__global__ __launch_bounds__(256) void k_gat(const float* __restrict__ features,
                                             const float* __restrict__ Wfc,
                                             const float* __restrict__ Wres,
                                             const float* __restrict__ bias,
                                             const float* __restrict__ wl,   // [8][256] transposed
                                             const float* __restrict__ wr,
                                             const int* __restrict__ url,
                                             const int* __restrict__ fill, const int* __restrict__ slist,
                                             float* __restrict__ gemb){
    int t = threadIdx.x;
    int lane = t & 63, wv = t >> 6;
    int u0 = blockIdx.x * 4;

    __shared__ float cxs[4][8][256];         // 32 KB
    __shared__ float fres[4][256];           //  4 KB
    __shared__ float sew[4][64][8];          //  8 KB
    __shared__ float ser[4][8];
    __shared__ int   sslist[4][64];

    for(int i = t; i < 4*64*8; i += 256) ((float*)sew)[i] = 0.f;

    float4 rwl[8], rwr[8];
    #pragma unroll
    for(int h = 0; h < 8; h++){
        rwl[h] = *(const float4*)&wl[h*256 + 4*lane];
        rwr[h] = *(const float4*)&wr[h*256 + 4*lane];
    }

    int dg[4], nj[4];
    #pragma unroll
    for(int j = 0; j < 4; j++){
        int u = u0 + j;
        dg[j] = min(fill[u], 64);
        nj[j] = clampi(url[u] - 1, 0, Nn - 1);
        if(t < dg[j]) sslist[j][t] = slist[u*64 + t];
        fres[j][t] = features[(size_t)nj[j] * FSz + t];
    }
    __syncthreads();

    // ---- pass A: wave-level dot products; tasks = all edges + 4 er rows
    int c1 = dg[0], c2 = c1 + dg[1], c3 = c2 + dg[2];
    int total = c3 + dg[3];
    for(int tau = wv; tau < total + 4; tau += 4){
        int j, i, isEr = 0;
        if(tau < c1){ j = 0; i = tau; }
        else if(tau < c2){ j = 1; i = tau - c1; }
        else if(tau < c3){ j = 2; i = tau - c2; }
        else if(tau < total){ j = 3; i = tau - c3; }
        else { j = tau - total; i = 0; isEr = 1; }
        int s = isEr ? nj[j] : sslist[j][i];
        float4 x = *(const float4*)(features + (size_t)s * FSz + 4*lane);
        float p[8];
        if(isEr){
            #pragma unroll
            for(int h = 0; h < 8; h++)
                p[h] = x.x*rwr[h].x + x.y*rwr[h].y + x.z*rwr[h].z + x.w*rwr[h].w;
        } else {
            #pragma unroll
            for(int h = 0; h < 8; h++)
                p[h] = x.x*rwl[h].x + x.y*rwl[h].y + x.z*rwl[h].z + x.w*rwl[h].w;
        }
        #pragma unroll
        for(int h = 0; h < 8; h++){
            #pragma unroll
            for(int m = 32; m >= 1; m >>= 1) p[h] += __shfl_xor(p[h], m, 64);
        }
        if(lane == 0){
            if(isEr){
                #pragma unroll
                for(int h = 0; h < 8; h++) ser[j][h] = p[h];
            } else {
                #pragma unroll
                for(int h = 0; h < 8; h++) sew[j][i][h] = p[h];
            }
        }
    }
    __syncthreads();
    // ---- softmax per (slot, head)
    if(t < 32){
        int j = t >> 3, h = t & 7;
        int dgj = dg[j];
        if(dgj > 0){
            float ern = ser[j][h];
            float m = -1e30f;
            for(int i = 0; i < dgj; i++){
                float v = sew[j][i][h] + ern;
                v = v > 0.f ? v : 0.2f * v;
                m = fmaxf(m, v);
            }
            float sum = 0.f;
            for(int i = 0; i < dgj; i++){
                float v = sew[j][i][h] + ern;
                v = v > 0.f ? v : 0.2f * v;
                float w = expf(v - m);
                sum += w;
                sew[j][i][h] = w;
            }
            float inv = 1.0f / fmaxf(sum, 1e-20f);
            for(int i = 0; i < dgj; i++) sew[j][i][h] *= inv;
        }
    }
    __syncthreads();
    // ---- pass B: alpha-combine; i-outer so 4 gathers fly concurrently
    {
        float cx[4][8];
        #pragma unroll
        for(int j = 0; j < 4; j++)
            #pragma unroll
            for(int h = 0; h < 8; h++) cx[j][h] = 0.f;
        int mxd = max(max(dg[0], dg[1]), max(dg[2], dg[3]));
        for(int i = 0; i < mxd; i++){
            float x[4];
            #pragma unroll
            for(int j = 0; j < 4; j++){
                int s = (i < dg[j]) ? sslist[j][i] : 0;
                x[j] = features[(size_t)s * FSz + t];
            }
            #pragma unroll
            for(int j = 0; j < 4; j++){
                const float* av = &sew[j][i][0];
                float xm = (i < dg[j]) ? x[j] : 0.f;
                #pragma unroll
                for(int h = 0; h < 8; h++) cx[j][h] += av[h] * xm;
            }
        }
        #pragma unroll
        for(int j = 0; j < 4; j++)
            #pragma unroll
            for(int h = 0; h < 8; h++) cxs[j][h][t] = cx[j][h];
    }
    __syncthreads();

    // ---- quad GEMV
    int h = t >> 5;
    int o0 = 2 * t;
    const float2* Wfc2  = (const float2*)Wfc;
    const float2* Wres2 = (const float2*)Wres;
    float a[4][2] = {{0,0},{0,0},{0,0},{0,0}};
    for(int f = 0; f < 256; f += 4){
        float2 w0 = Wfc2[(f+0)*256 + t];
        float2 w1 = Wfc2[(f+1)*256 + t];
        float2 w2 = Wfc2[(f+2)*256 + t];
        float2 w3 = Wfc2[(f+3)*256 + t];
        float2 r0 = Wres2[(f+0)*256 + t];
        float2 r1 = Wres2[(f+1)*256 + t];
        float2 r2 = Wres2[(f+2)*256 + t];
        float2 r3 = Wres2[(f+3)*256 + t];
        #pragma unroll
        for(int j = 0; j < 4; j++){
            float4 c = *(const float4*)&cxs[j][h][f];
            float4 x = *(const float4*)&fres[j][f];
            a[j][0] += c.x*w0.x + c.y*w1.x + c.z*w2.x + c.w*w3.x
                     + x.x*r0.x + x.y*r1.x + x.z*r2.x + x.w*r3.x;
            a[j][1] += c.x*w0.y + c.y*w1.y + c.z*w2.y + c.w*w3.y
                     + x.x*r0.y + x.y*r1.y + x.z*r2.y + x.w*r3.y;
        }
    }
    float b0 = bias[o0], b1 = bias[o0 + 1];
    #pragma unroll
    for(int j = 0; j < 4; j++){
        float2* gp = (float2*)(gemb + (size_t)(u0 + j) * HD_);
        gp[t] = make_float2(a[j][0] + b0, a[j][1] + b1);
    }
}

// K4: TWO batch elements per block — weights (wq/wk/wv/fcw, 2 MB L2/block)
// stream once and feed both elements (k_mha was L2-BW-bound: 8 MB/CU ≈ 53 µs).
__global__ __launch_bounds__(256, 2) void k_mha(const float* __restrict__ gemb,
                                             const float* __restrict__ lng, const float* __restrict__ lnb,
                                             const float* __restrict__ wq, const float* __restrict__ wk,
                                             const float* __restrict__ wvp, const float* __restrict__ fcw,
                                             const float* __restrict__ fcb, const float* __restrict__ mlg,
                                             const float* __restrict__ mlb, const float* __restrict__ outw,
                                             const float* __restrict__ outb, float* __restrict__ out){
    __shared__ float A[2][512];                // xr -> sc -> yy
    __shared__ float xnF[2][512];              // fp32 LN1 out (residual)
    __shared__ unsigned short xnT[2][512];     // bf16 LN1 out, [d*8+q]
    __shared__ unsigned short qkb[2][8320];    // per elem: bf16 q | k ; k-region reused for fp32 partials
    __shared__ float mu8[2][8], rs8[2][8], pooled[2][64];

    int t = threadIdx.x;
    int lane = t & 63, wv = t >> 6;
    int e0 = blockIdx.x * 2;

    {
        const float* g0 = gemb + (size_t)e0 * HD_;
        const float* g1 = gemb + (size_t)(e0 + 1) * HD_;
        A[0][t] = g0[t]; A[0][t + 256] = g0[t + 256];
        A[1][t] = g1[t]; A[1][t + 256] = g1[t + 256];
    }
    __syncthreads();
    if(t < 16){
        int ee = t >> 3, q = t & 7;
        float s = 0.f, s2 = 0.f;
        for(int d = 0; d < 64; d++){ float v = A[ee][q*64 + d]; s += v; s2 += v * v; }
        float mu = s * (1.0f/64.0f);
        float var = s2 * (1.0f/64.0f) - mu * mu;
        mu8[ee][q] = mu; rs8[ee][q] = rsqrtf(fmaxf(var, 0.0f) + 1e-6f);
    }
    __syncthreads();
    #pragma unroll
    for(int p = 0; p < 4; p++){
        int i = p*256 + t; int ee = i >> 9, ii = i & 511, q = ii >> 6, d = ii & 63;
        float xv = (A[ee][ii] - mu8[ee][q]) * rs8[ee][q] * lng[d] + lnb[d];
        xnF[ee][ii] = xv;
        xnT[ee][d*8 + q] = f2bf(xv);
    }
    __syncthreads();
    // ---- fused q,k,v projection for BOTH elems; thread owns cols t, t+256 ----
    float aq0[2][8], aq1[2][8], ak0[2][8], ak1[2][8], av0[2][8], av1[2][8];
    #pragma unroll
    for(int ee = 0; ee < 2; ee++)
        #pragma unroll
        for(int r = 0; r < 8; r++){
            aq0[ee][r]=0.f; aq1[ee][r]=0.f; ak0[ee][r]=0.f;
            ak1[ee][r]=0.f; av0[ee][r]=0.f; av1[ee][r]=0.f;
        }
    #pragma unroll 2
    for(int d = 0; d < 64; d++){
        float q0 = wq[d*512 + t],  q1 = wq[d*512 + t + 256];
        float k0 = wk[d*512 + t],  k1 = wk[d*512 + t + 256];
        float v0 = wvp[d*512 + t], v1 = wvp[d*512 + t + 256];
        #pragma unroll
        for(int ee = 0; ee < 2; ee++){
            uint4 xp = *(const uint4*)&xnT[ee][d*8];
            float xv[8] = { bflo(xp.x), bfhi(xp.x), bflo(xp.y), bfhi(xp.y),
                            bflo(xp.z), bfhi(xp.z), bflo(xp.w), bfhi(xp.w) };
            #pragma unroll
            for(int r = 0; r < 8; r++){
                aq0[ee][r] += xv[r]*q0; aq1[ee][r] += xv[r]*q1;
                ak0[ee][r] += xv[r]*k0; ak1[ee][r] += xv[r]*k1;
                av0[ee][r] += xv[r]*v0; av1[ee][r] += xv[r]*v1;
            }
        }
    }
    #pragma unroll
    for(int ee = 0; ee < 2; ee++)
        #pragma unroll
        for(int qq = 0; qq < 8; qq++){
            qkb[ee][qq*520 + t]              = f2bf(aq0[ee][qq]);
            qkb[ee][qq*520 + t + 256]        = f2bf(aq1[ee][qq]);
            qkb[ee][4160 + qq*520 + t]       = f2bf(ak0[ee][qq]);
            qkb[ee][4160 + qq*520 + t + 256] = f2bf(ak1[ee][qq]);
        }
    __syncthreads();
    // ---- scores: 1024 tasks across both elems ----
    #pragma unroll
    for(int p = 0; p < 4; p++){
        int i = p*256 + t;
        int ee = i >> 9, idx = i & 511;
        int nh = idx >> 6, qq = (idx >> 3) & 7, kk = idx & 7;
        const unsigned short* qrow = &qkb[ee][qq*520 + nh*64];
        const unsigned short* krow = &qkb[ee][4160 + kk*520 + nh*64];
        float s = 0.f;
        #pragma unroll
        for(int d8 = 0; d8 < 64; d8 += 8){
            uint4 qv = *(const uint4*)&qrow[d8];
            uint4 kv = *(const uint4*)&krow[d8];
            s += bflo(qv.x)*bflo(kv.x) + bfhi(qv.x)*bfhi(kv.x)
               + bflo(qv.y)*bflo(kv.y) + bfhi(qv.y)*bfhi(kv.y)
               + bflo(qv.z)*bflo(kv.z) + bfhi(qv.z)*bfhi(kv.z)
               + bflo(qv.w)*bflo(kv.w) + bfhi(qv.w)*bfhi(kv.w);
        }
        A[ee][idx] = s * 0.125f;
    }
    __syncthreads();
    if(t < 128){
        int ee = t >> 6, row = t & 63;
        float mx = -1e30f;
        #pragma unroll
        for(int k = 0; k < 8; k++) mx = fmaxf(mx, A[ee][row*8 + k]);
        float e[8]; float s = 0.f;
        #pragma unroll
        for(int k = 0; k < 8; k++){ e[k] = expf(A[ee][row*8 + k] - mx); s += e[k]; }
        float inv = 1.0f / s;
        #pragma unroll
        for(int k = 0; k < 8; k++) A[ee][row*8 + k] = e[k] * inv;
    }
    __syncthreads();
    // ---- attn @ v (v in registers) -> ov (bf16) into q regions ----
    {
        int nh0 = wv;
        #pragma unroll
        for(int ee = 0; ee < 2; ee++){
            #pragma unroll
            for(int qq = 0; qq < 8; qq++){
                const float* s0 = &A[ee][nh0*64 + qq*8];
                const float* s1 = &A[ee][(nh0+4)*64 + qq*8];
                float4 a0 = *(const float4*)s0, b0 = *(const float4*)(s0 + 4);
                float4 a1 = *(const float4*)s1, b1 = *(const float4*)(s1 + 4);
                float o0 = a0.x*av0[ee][0] + a0.y*av0[ee][1] + a0.z*av0[ee][2] + a0.w*av0[ee][3]
                         + b0.x*av0[ee][4] + b0.y*av0[ee][5] + b0.z*av0[ee][6] + b0.w*av0[ee][7];
                float o1 = a1.x*av1[ee][0] + a1.y*av1[ee][1] + a1.z*av1[ee][2] + a1.w*av1[ee][3]
                         + b1.x*av1[ee][4] + b1.y*av1[ee][5] + b1.z*av1[ee][6] + b1.w*av1[ee][7];
                qkb[ee][qq*520 + t]       = f2bf(o0);
                qkb[ee][qq*520 + t + 256] = f2bf(o1);
            }
        }
    }
    __syncthreads();
    // ---- fc wave-split: wave wv owns k-range for BOTH elems (fcw read once) ----
    {
        float* P0 = (float*)&qkb[0][4160];   // 8 KB partials per elem (k regions dead)
        float* P1 = (float*)&qkb[1][4160];
        int g = lane & 31;
        int qh = lane >> 5;
        int k0r = wv * 128;
        float a[2][4][2];
        #pragma unroll
        for(int ee = 0; ee < 2; ee++)
            #pragma unroll
            for(int jq = 0; jq < 4; jq++){ a[ee][jq][0] = 0.f; a[ee][jq][1] = 0.f; }
        const float2* fw2 = (const float2*)fcw;   // [512][32] float2
        for(int k = k0r; k < k0r + 128; k += 8){
            float2 f0 = fw2[(k+0)*32 + g];
            float2 f1 = fw2[(k+1)*32 + g];
            float2 f2 = fw2[(k+2)*32 + g];
            float2 f3 = fw2[(k+3)*32 + g];
            float2 f4 = fw2[(k+4)*32 + g];
            float2 f5 = fw2[(k+5)*32 + g];
            float2 f6 = fw2[(k+6)*32 + g];
            float2 f7 = fw2[(k+7)*32 + g];
            #pragma unroll
            for(int ee = 0; ee < 2; ee++){
                #pragma unroll
                for(int jq = 0; jq < 4; jq++){
                    int qq = qh*4 + jq;
                    uint4 op = *(const uint4*)&qkb[ee][qq*520 + k];
                    float x0 = bflo(op.x), x1 = bfhi(op.x), x2 = bflo(op.y), x3 = bfhi(op.y);
                    float x4 = bflo(op.z), x5 = bfhi(op.z), x6 = bflo(op.w), x7 = bfhi(op.w);
                    a[ee][jq][0] += x0*f0.x + x1*f1.x + x2*f2.x + x3*f3.x + x4*f4.x + x5*f5.x + x6*f6.x + x7*f7.x;
                    a[ee][jq][1] += x0*f0.y + x1*f1.y + x2*f2.y + x3*f3.y + x4*f4.y + x5*f5.y + x6*f6.y + x7*f7.y;
                }
            }
        }
        __syncthreads();
        #pragma unroll
        for(int jq = 0; jq < 4; jq++){
            int qq = qh*4 + jq;
            *(float2*)&P0[wv*512 + qq*64 + 2*g] = make_float2(a[0][jq][0], a[0][jq][1]);
            *(float2*)&P1[wv*512 + qq*64 + 2*g] = make_float2(a[1][jq][0], a[1][jq][1]);
        }
        __syncthreads();
        #pragma unroll
        for(int p = 0; p < 4; p++){
            int i = p*256 + t;
            int ee = i >> 9, o = i & 511, dd = o & 63;
            const float* P = ee ? P1 : P0;
            A[ee][o] = P[o] + P[512 + o] + P[1024 + o] + P[1536 + o] + fcb[dd] + xnF[ee][o];
        }
    }
    __syncthreads();
    if(t < 16){
        int ee = t >> 3, q = t & 7;
        float s = 0.f, s2 = 0.f;
        for(int d = 0; d < 64; d++){ float v = A[ee][q*64 + d]; s += v; s2 += v * v; }
        float mu = s * (1.0f/64.0f);
        float var = s2 * (1.0f/64.0f) - mu * mu;
        mu8[ee][q] = mu; rs8[ee][q] = rsqrtf(fmaxf(var, 0.0f) + 1e-6f);
    }
    __syncthreads();
    if(t < 128){
        int ee = t >> 6, dd = t & 63;
        float g2 = mlg[dd], bb = mlb[dd];
        float s = 0.f;
        #pragma unroll
        for(int qq = 0; qq < 8; qq++)
            s += (A[ee][qq*64 + dd] - mu8[ee][qq]) * rs8[ee][qq] * g2 + bb;
        pooled[ee][dd] = s;
    }
    __syncthreads();
    if(t < 4){
        int ee = t >> 1, c = t & 1;
        float s = outb[c];
        for(int d = 0; d < 64; d++) s += pooled[ee][d] * outw[d*2 + c];
        out[(e0 + ee)*2 + c] = s;
    }
}

extern "C" void kernel_launch(void* const* d_in, const int* in_sizes, int n_in,
                              void* d_out, int out_size, void* d_ws, size_t ws_size,
                              hipStream_t stream){
    (void)in_sizes; (void)n_in; (void)out_size; (void)ws_size;
    const float* features  = (const float*)d_in[0];
    const int*   src       = (const int*)d_in[1];
    const int*   dst       = (const int*)d_in[2];
    const int*   url       = (const int*)d_in[3];
    const float* gat_fc_w  = (const float*)d_in[4];
    const float* attn_l    = (const float*)d_in[5];
    const float* attn_r    = (const float*)d_in[6];
    const float* gat_res_w = (const float*)d_in[7];
    const float* gat_bias  = (const float*)d_in[8];
    const float* ln_g      = (const float*)d_in[9];
    const float* ln_b      = (const float*)d_in[10];
    const float* wq        = (const float*)d_in[11];
    const float* wk        = (const float*)d_in[12];
    const float* wv        = (const float*)d_in[13];
    const float* fc_w      = (const float*)d_in[14];
    const float* fc_b      = (const float*)d_in[15];
    const float* mha_ln_g  = (const float*)d_in[16];
    const float* mha_ln_b  = (const float*)d_in[17];
    const float* out_w     = (const float*)d_in[18];
    const float* out_b     = (const float*)d_in[19];

    char* base = (char*)d_ws;
    size_t cur = 0;
    auto alloc = [&](size_t nbytes) -> void* {
        void* p = base + cur;
        cur = (cur + nbytes + 255) & ~(size_t)255;
        return p;
    };
    float* wl    = (float*)alloc(2048 * sizeof(float));   // transposed [8][256]
    float* wr    = (float*)alloc(2048 * sizeof(float));
    int*   fill  = (int*)alloc(1024 * sizeof(int));
    int*   slist = (int*)alloc((size_t)1024 * 64 * sizeof(int));
    float* gemb  = (float*)alloc((size_t)1024 * 512 * sizeof(float));

    hipMemsetAsync(fill, 0, 1024 * sizeof(int), stream);

    hipLaunchKernelGGL(k_scatter, dim3(1579), dim3(256), 0, stream, src, dst, url, fill, slist,
                       gat_fc_w, attn_l, attn_r, wl, wr);
    hipLaunchKernelGGL(k_gat,     dim3(256),  dim3(256), 0, stream, features, gat_fc_w, gat_res_w, gat_bias,
                       wl, wr, url, fill, slist, gemb);
    hipLaunchKernelGGL(k_mha,     dim3(512),  dim3(256), 0, stream, gemb, ln_g, ln_b,
                       wq, wk, wv, fc_w, fc_b, mha_ln_g, mha_ln_b, out_w, out_b,
                       (float*)d_out);
}